// Round 4
// baseline (1380.127 us; speedup 1.0000x reference)
//
#include <hip/hip_runtime.h>
#include <math.h>

typedef __attribute__((ext_vector_type(8))) short bf16x8;
typedef __attribute__((ext_vector_type(4))) float f32x4;
typedef __attribute__((ext_vector_type(4))) unsigned short u16x4;

static __device__ __forceinline__ short f2bf(float f) {
  unsigned u = __builtin_bit_cast(unsigned, f);
  u += 0x7fffu + ((u >> 16) & 1u);
  return (short)(u >> 16);
}
static __device__ __forceinline__ float bf2f(unsigned short s) {
  unsigned u = ((unsigned)s) << 16;
  return __builtin_bit_cast(float, u);
}
static __device__ __forceinline__ f32x4 mfma16(bf16x8 a, bf16x8 b, f32x4 c) {
  return __builtin_amdgcn_mfma_f32_16x16x32_bf16(a, b, c, 0, 0, 0);
}
static __device__ __forceinline__ bf16x8 pack8v(f32x4 a, f32x4 b) {
  bf16x8 r;
  r[0]=f2bf(a[0]); r[1]=f2bf(a[1]); r[2]=f2bf(a[2]); r[3]=f2bf(a[3]);
  r[4]=f2bf(b[0]); r[5]=f2bf(b[1]); r[6]=f2bf(b[2]); r[7]=f2bf(b[3]);
  return r;
}

// ---------------- cast item_emb -> bf16 (row-major) ----------------
__global__ __launch_bounds__(256) void cast_ebf(const float* __restrict__ E, short* __restrict__ Ebf) {
  int i = blockIdx.x * 256 + threadIdx.x;
  if (i < 50001 * 128) Ebf[i] = f2bf(E[i]);
}

// ---------------- build E^T bf16 [128][50048] (zero-padded) ----------------
__global__ __launch_bounds__(256) void build_et(const float* __restrict__ E, short* __restrict__ Et) {
  __shared__ float tile[64][132];
  const int v0 = blockIdx.x * 64;
  const int tid = threadIdx.x;
  const int r = tid >> 2, ks = (tid & 3) * 32;
  const int v = v0 + r;
  for (int j = 0; j < 32; j += 4) {
    f32x4 x = {0.f, 0.f, 0.f, 0.f};
    if (v < 50001) x = *(const f32x4*)(E + (size_t)v * 128 + ks + j);
    *(f32x4*)&tile[r][ks + j] = x;
  }
  __syncthreads();
  const int k = tid >> 1, vs = (tid & 1) * 32;
  for (int j = 0; j < 32; ++j)
    Et[(size_t)k * 50048 + v0 + vs + j] = f2bf(tile[vs + j][k]);
}

// ---------------- gi = x @ Wih^T for all (row, t): parallel gather + MFMA ----------------
// gi tile layout: per tile (16 batch rows at one t): [gate(3)][col(128)][row(16)] bf16 (6144 ushorts)
// tile index within behavior = r0blk * T + t
__global__ __launch_bounds__(512) void gi_gemm_kernel(
    const int* __restrict__ seq0, const int* __restrict__ seq1,
    const int* __restrict__ seq2, const int* __restrict__ seq3,
    const float* __restrict__ item_emb, const float* __restrict__ Wih,
    unsigned short* __restrict__ gi_t50, unsigned short* __restrict__ gi_click)
{
  const int b = blockIdx.x;           // 700 blocks, 16 tiles each
  int beh, tile0;
  if (b < 100)      { beh = 0; tile0 = b * 16; }
  else if (b < 200) { beh = 1; tile0 = (b - 100) * 16; }
  else if (b < 300) { beh = 2; tile0 = (b - 200) * 16; }
  else              { beh = 3; tile0 = (b - 300) * 16; }
  const int T = (beh == 3) ? 200 : 50;
  const int* seq = (beh == 0) ? seq0 : (beh == 1) ? seq1 : (beh == 2) ? seq2 : seq3;
  unsigned short* gibase = (beh == 3) ? gi_click : (gi_t50 + (size_t)beh * 1600 * 6144);

  const int tid = threadIdx.x;
  const int wave = tid >> 6, lane = tid & 63, lrow = lane & 15, lk8 = lane >> 4;
  const int bcol = wave * 16 + lrow;

  // Wih B-fragments (rows g*128 + bcol), 12 frags = 48 VGPR
  bf16x8 wif[3][4];
  const float* WihB = Wih + (size_t)beh * 384 * 128;
#pragma unroll
  for (int g = 0; g < 3; ++g) {
    const int wr = g * 128 + bcol;
#pragma unroll
    for (int kt = 0; kt < 4; ++kt) {
      const int k0 = kt * 32 + lk8 * 8;
      f32x4 a0 = *(const f32x4*)(WihB + (size_t)wr * 128 + k0);
      f32x4 a1 = *(const f32x4*)(WihB + (size_t)wr * 128 + k0 + 4);
      wif[g][kt] = pack8v(a0, a1);
    }
  }

  __shared__ short xt[16][132];
  const int gj = tid >> 5;            // gather row 0..15
  const int gc = (tid & 31) * 4;      // gather col 0..124

  for (int ti = 0; ti < 16; ++ti) {
    const int tile = tile0 + ti;
    const int r0blk = tile / T;
    const int t = tile - r0blk * T;
    {
      const int sidx = seq[(size_t)(r0blk * 16 + gj) * T + t];
      const f32x4 xv = *(const f32x4*)(item_emb + (size_t)sidx * 128 + gc);
      xt[gj][gc]     = f2bf(xv[0]);
      xt[gj][gc + 1] = f2bf(xv[1]);
      xt[gj][gc + 2] = f2bf(xv[2]);
      xt[gj][gc + 3] = f2bf(xv[3]);
    }
    __syncthreads();
    bf16x8 ax[4];
#pragma unroll
    for (int kt = 0; kt < 4; ++kt)
      ax[kt] = *(const bf16x8*)&xt[lrow][kt * 32 + lk8 * 8];
    f32x4 acc[3] = {{0,0,0,0},{0,0,0,0},{0,0,0,0}};
#pragma unroll
    for (int kt = 0; kt < 4; ++kt) {
      acc[0] = mfma16(ax[kt], wif[0][kt], acc[0]);
      acc[1] = mfma16(ax[kt], wif[1][kt], acc[1]);
      acc[2] = mfma16(ax[kt], wif[2][kt], acc[2]);
    }
    unsigned short* dst = gibase + (size_t)tile * 6144 + ((size_t)bcol * 16 + lk8 * 4);
#pragma unroll
    for (int g = 0; g < 3; ++g) {
      u16x4 o;
      o[0] = (unsigned short)f2bf(acc[g][0]);
      o[1] = (unsigned short)f2bf(acc[g][1]);
      o[2] = (unsigned short)f2bf(acc[g][2]);
      o[3] = (unsigned short)f2bf(acc[g][3]);
      *(u16x4*)(dst + (size_t)g * 2048) = o;
    }
    __syncthreads();
  }
}

// ---------------- GRU recurrence on precomputed gi: 12 MFMA + epilogue per step ----------------
__global__ __launch_bounds__(512, 2) void gru_rec2_kernel(
    const float* __restrict__ Whh, const float* __restrict__ bih,
    const float* __restrict__ bhh,
    const unsigned short* __restrict__ gi_t50,
    const unsigned short* __restrict__ gi_click,
    float* __restrict__ e_out)
{
  const int beh = blockIdx.x >> 5;
  const int r0blk = blockIdx.x & 31;
  const int r0 = r0blk * 16;
  const int T = (beh == 3) ? 200 : 50;
  const unsigned short* gib =
      ((beh == 3) ? gi_click : (gi_t50 + (size_t)beh * 1600 * 6144)) + (size_t)r0blk * T * 6144;

  const int tid = threadIdx.x;
  const int wave = tid >> 6;
  const int lane = tid & 63;
  const int lrow = lane & 15;
  const int lk8 = lane >> 4;
  const int bcol = wave * 16 + lrow;

  __shared__ short h0[16][140];
  __shared__ short h1[16][140];

  // Whh B-fragments: 12 frags = 48 VGPR
  bf16x8 whf[3][4];
  const float* WhhB = Whh + (size_t)beh * 384 * 128;
#pragma unroll
  for (int g = 0; g < 3; ++g) {
    const int wr = g * 128 + bcol;
#pragma unroll
    for (int kt = 0; kt < 4; ++kt) {
      const int k0 = kt * 32 + lk8 * 8;
      f32x4 b0 = *(const f32x4*)(WhhB + (size_t)wr * 128 + k0);
      f32x4 b1 = *(const f32x4*)(WhhB + (size_t)wr * 128 + k0 + 4);
      whf[g][kt] = pack8v(b0, b1);
    }
  }
  const float bir = bih[beh * 384 + bcol];
  const float biz = bih[beh * 384 + 128 + bcol];
  const float bin_ = bih[beh * 384 + 256 + bcol];
  const float bhr = bhh[beh * 384 + bcol];
  const float bhz = bhh[beh * 384 + 128 + bcol];
  const float bhn = bhh[beh * 384 + 256 + bcol];

  for (int i = tid; i < 16 * 140; i += 512) ((short*)h0)[i] = 0;
  float hreg[4] = {0.f, 0.f, 0.f, 0.f};
  __syncthreads();

  const unsigned short* gip = gib + ((size_t)bcol * 16 + lk8 * 4);

  // prefetch t=0
  u16x4 gp[3];
#pragma unroll
  for (int g = 0; g < 3; ++g) gp[g] = *(const u16x4*)(gip + (size_t)g * 2048);

  short (*hin)[140] = h0;
  short (*hout)[140] = h1;

  for (int t = 0; t < T; ++t) {
    u16x4 gc0 = gp[0], gc1 = gp[1], gc2 = gp[2];
    if (t + 1 < T) {
      const unsigned short* np = gip + (size_t)(t + 1) * 6144;
#pragma unroll
      for (int g = 0; g < 3; ++g) gp[g] = *(const u16x4*)(np + (size_t)g * 2048);
    }

    bf16x8 ah[4];
#pragma unroll
    for (int kt = 0; kt < 4; ++kt)
      ah[kt] = *(const bf16x8*)&hin[lrow][kt * 32 + lk8 * 8];

    f32x4 hr = {0,0,0,0}, hz = {0,0,0,0}, hn = {0,0,0,0};
#pragma unroll
    for (int kt = 0; kt < 4; ++kt) {
      hr = mfma16(ah[kt], whf[0][kt], hr);
      hz = mfma16(ah[kt], whf[1][kt], hz);
      hn = mfma16(ah[kt], whf[2][kt], hn);
    }
#pragma unroll
    for (int e2 = 0; e2 < 4; ++e2) {
      const float gir = bf2f(gc0[e2]);
      const float giz = bf2f(gc1[e2]);
      const float gin = bf2f(gc2[e2]);
      const float rr = __fdividef(1.f, 1.f + __expf(-(gir + bir + hr[e2] + bhr)));
      const float zz = __fdividef(1.f, 1.f + __expf(-(giz + biz + hz[e2] + bhz)));
      const float ty = __expf(-2.f * (gin + bin_ + rr * (hn[e2] + bhn)));
      const float nn = __fdividef(1.f - ty, 1.f + ty);   // tanh
      hreg[e2] = (1.f - zz) * nn + zz * hreg[e2];
      hout[lk8 * 4 + e2][bcol] = f2bf(hreg[e2]);
    }
    __syncthreads();
    short (*tmp)[140] = hin; hin = hout; hout = tmp;
  }

#pragma unroll
  for (int e2 = 0; e2 < 4; ++e2)
    e_out[(size_t)(r0 + lk8 * 4 + e2) * 512 + bcol * 4 + beh] = hreg[e2];
}

// ---------------- caps: c = softmax(b), v = alpha * sum_h c*u, v_ = ||v||*ws+bias (512 thr, h-split) ----------------
__global__ __launch_bounds__(512) void caps_v_kernel(
    const float* __restrict__ b_state, const float* __restrict__ e_buf,
    const float* __restrict__ W, const float* __restrict__ w_scale,
    const float* __restrict__ bias_vec, const float* __restrict__ alpha,
    float* __restrict__ v_buf, float* __restrict__ vn_buf)
{
  __shared__ float e_lds[4][128][4];
  __shared__ float stat_m[4][128];
  __shared__ float stat_i[4][128];
  __shared__ float red[256][4][4];
  const int g0 = blockIdx.x * 4;
  const int tid = threadIdx.x;
  for (int i = tid; i < 2048; i += 512) ((float*)e_lds)[i] = e_buf[(size_t)g0 * 512 + i];
  const int wv = tid >> 6, ln = tid & 63;
  for (int ri = wv; ri < 512; ri += 8) {
    const int g = ri >> 7, h = ri & 127;
    const float* row = b_state + (size_t)(g0 + g) * 16384 + h * 128;
    const float x0 = row[ln], x1 = row[ln + 64];
    float m = fmaxf(x0, x1);
#pragma unroll
    for (int off = 32; off > 0; off >>= 1) m = fmaxf(m, __shfl_xor(m, off));
    float s = __expf(x0 - m) + __expf(x1 - m);
#pragma unroll
    for (int off = 32; off > 0; off >>= 1) s += __shfl_xor(s, off);
    if (ln == 0) { stat_m[g][h] = m; stat_i[g][h] = 1.f / s; }
  }
  __syncthreads();
  const int half = tid >> 8;
  const int t8 = tid & 255;
  const int c = t8 >> 1, dh = (t8 & 1) * 4;
  f32x4 acc[4] = {{0,0,0,0},{0,0,0,0},{0,0,0,0},{0,0,0,0}};
  const int hbeg = half * 64, hend = hbeg + 64;
  for (int h = hbeg; h < hend; ++h) {
    float cv[4];
#pragma unroll
    for (int g = 0; g < 4; ++g)
      cv[g] = __expf(b_state[(size_t)(g0 + g) * 16384 + h * 128 + c] - stat_m[g][h]) * stat_i[g][h];
#pragma unroll
    for (int t4 = 0; t4 < 4; ++t4) {
      const f32x4 w4 = *(const f32x4*)(W + ((size_t)(h * 4 + t4) * 128 + c) * 8 + dh);
#pragma unroll
      for (int g = 0; g < 4; ++g) acc[g] += (cv[g] * e_lds[g][h][t4]) * w4;
    }
  }
  if (half == 1) {
#pragma unroll
    for (int g = 0; g < 4; ++g) *(f32x4*)&red[t8][g][0] = acc[g];
  }
  __syncthreads();
  if (half == 0) {
    const float al = alpha[0];
#pragma unroll
    for (int g = 0; g < 4; ++g) {
      acc[g] = (acc[g] + *(const f32x4*)&red[t8][g][0]) * al;
      *(f32x4*)(v_buf + (size_t)(g0 + g) * 1024 + c * 8 + dh) = acc[g];
      float ss = acc[g][0]*acc[g][0] + acc[g][1]*acc[g][1] + acc[g][2]*acc[g][2] + acc[g][3]*acc[g][3];
      ss += __shfl_xor(ss, 1);
      if ((tid & 1) == 0) vn_buf[(g0 + g) * 128 + c] = sqrtf(ss) * w_scale[c] + bias_vec[c];
    }
  }
}

// ---------------- logits = vn @ E^T (MFMA bf16), into d_out ----------------
__global__ __launch_bounds__(512) void logits_kernel(
    const float* __restrict__ vn, const short* __restrict__ Ebf,
    float* __restrict__ out)
{
  __shared__ short et[64][136];
  const int n0 = blockIdx.x * 64;
  const int m0 = blockIdx.y * 128;
  const int tid = threadIdx.x;
  const int wave = tid >> 6, lane = tid & 63, lrow = lane & 15, lk8 = lane >> 4;
  {
    const int r = tid >> 3, ks = (tid & 7) * 16;
    const int v = n0 + r;
    bf16x8 a = {0,0,0,0,0,0,0,0}, b = {0,0,0,0,0,0,0,0};
    if (v < 50001) {
      a = *(const bf16x8*)(Ebf + (size_t)v * 128 + ks);
      b = *(const bf16x8*)(Ebf + (size_t)v * 128 + ks + 8);
    }
    *(bf16x8*)&et[r][ks] = a;
    *(bf16x8*)&et[r][ks + 8] = b;
  }
  __syncthreads();
  const int arow = m0 + wave * 16 + lrow;
  bf16x8 afr[4];
#pragma unroll
  for (int kt = 0; kt < 4; ++kt) {
    const float* p = vn + (size_t)arow * 128 + kt * 32 + lk8 * 8;
    afr[kt] = pack8v(*(const f32x4*)p, *(const f32x4*)(p + 4));
  }
  f32x4 acc[4] = {{0,0,0,0},{0,0,0,0},{0,0,0,0},{0,0,0,0}};
#pragma unroll
  for (int kt = 0; kt < 4; ++kt) {
#pragma unroll
    for (int nt = 0; nt < 4; ++nt) {
      const bf16x8 bfr = *(const bf16x8*)&et[nt * 16 + lrow][kt * 32 + lk8 * 8];
      acc[nt] = mfma16(afr[kt], bfr, acc[nt]);
    }
  }
#pragma unroll
  for (int nt = 0; nt < 4; ++nt) {
    const int col = n0 + nt * 16 + lrow;
    if (col < 50001) {
      const int row = m0 + wave * 16 + lk8 * 4;
#pragma unroll
      for (int e2 = 0; e2 < 4; ++e2)
        out[(size_t)(row + e2) * 50001 + col] = acc[nt][e2];
    }
  }
}

// ---------------- per-row softmax stats over 50001 logits ----------------
__global__ __launch_bounds__(256) void rowstats_kernel(
    const float* __restrict__ out, float* __restrict__ row_m, float* __restrict__ row_inv)
{
  const int b = blockIdx.x;
  const int tid = threadIdx.x;
  const float* row = out + (size_t)b * 50001;
  float m = -1e30f, s = 0.f;
  for (int i = tid; i < 50001; i += 256) {
    const float x = row[i];
    const float nm = fmaxf(m, x);
    s = s * __expf(m - nm) + __expf(x - nm);
    m = nm;
  }
#pragma unroll
  for (int off = 32; off > 0; off >>= 1) {
    const float m2 = __shfl_xor(m, off), s2 = __shfl_xor(s, off);
    const float nm = fmaxf(m, m2);
    s = s * __expf(m - nm) + s2 * __expf(m2 - nm);
    m = nm;
  }
  __shared__ float ms[4], ss[4];
  const int wv = tid >> 6, ln = tid & 63;
  if (ln == 0) { ms[wv] = m; ss[wv] = s; }
  __syncthreads();
  if (tid == 0) {
    float M = ms[0], S = ss[0];
    for (int w = 1; w < 4; ++w) {
      const float nm = fmaxf(M, ms[w]);
      S = S * __expf(M - nm) + ss[w] * __expf(ms[w] - nm);
      M = nm;
    }
    row_m[b] = M;
    row_inv[b] = 1.f / S;
  }
}

// ---------------- p = softmax(logits) @ E  (split-K MFMA, atomic accumulate) ----------------
__global__ __launch_bounds__(256) void pgemm_kernel(
    const float* __restrict__ out, const short* __restrict__ Et,
    const float* __restrict__ row_m, const float* __restrict__ row_inv,
    float* __restrict__ p_buf)
{
  const int tid = threadIdx.x;
  const int wave = tid >> 6, lane = tid & 63, lrow = lane & 15, lk8 = lane >> 4;
  const int m0 = blockIdx.y * 64;
  const int row = m0 + wave * 16 + lrow;
  const float rm = row_m[row], ri = row_inv[row];
  const float* lp = out + (size_t)row * 50001;
  const int kbeg = blockIdx.x * 1024;
  f32x4 acc[8] = {{0,0,0,0},{0,0,0,0},{0,0,0,0},{0,0,0,0},
                  {0,0,0,0},{0,0,0,0},{0,0,0,0},{0,0,0,0}};
  if (kbeg + 1024 <= 50001) {
    for (int v0 = kbeg; v0 < kbeg + 1024; v0 += 32) {
      const int kb = v0 + lk8 * 8;
      float x[8];
      __builtin_memcpy(x, lp + kb, 32);
      bf16x8 afr;
#pragma unroll
      for (int j = 0; j < 8; ++j) afr[j] = f2bf(__expf(x[j] - rm) * ri);
#pragma unroll
      for (int nt = 0; nt < 8; ++nt) {
        const bf16x8 bfr = *(const bf16x8*)(Et + (size_t)(nt * 16 + lrow) * 50048 + kb);
        acc[nt] = mfma16(afr, bfr, acc[nt]);
      }
    }
  } else {
    const int kend = 50001;
    for (int v0 = kbeg; v0 < kend; v0 += 32) {
      const int kb = v0 + lk8 * 8;
      float x[8];
#pragma unroll
      for (int j = 0; j < 8; ++j) x[j] = (kb + j < 50001) ? lp[kb + j] : rm - 100.f;
      bf16x8 afr;
#pragma unroll
      for (int j = 0; j < 8; ++j) afr[j] = f2bf(__expf(x[j] - rm) * ri);
#pragma unroll
      for (int nt = 0; nt < 8; ++nt) {
        const bf16x8 bfr = *(const bf16x8*)(Et + (size_t)(nt * 16 + lrow) * 50048 + kb);
        acc[nt] = mfma16(afr, bfr, acc[nt]);
      }
    }
  }
#pragma unroll
  for (int nt = 0; nt < 8; ++nt)
#pragma unroll
    for (int e2 = 0; e2 < 4; ++e2)
      atomicAdd(&p_buf[(size_t)(m0 + wave * 16 + lk8 * 4 + e2) * 128 + nt * 16 + lrow], acc[nt][e2]);
}

// ---------------- coef = concat(p, v) @ W_coef ----------------
__global__ __launch_bounds__(256) void coef_kernel(
    const float* __restrict__ p_buf, const float* __restrict__ v_buf,
    const float* __restrict__ W_coef, float* __restrict__ coef_buf)
{
  __shared__ float p_lds[4][128];
  const int g0 = blockIdx.x * 4;
  const int tid = threadIdx.x;
  for (int i = tid; i < 512; i += 256) ((float*)p_lds)[i] = p_buf[(size_t)g0 * 128 + i];
  __syncthreads();
  const int c = tid >> 1, dh = (tid & 1) * 4;
  float vg[4][8];
#pragma unroll
  for (int g = 0; g < 4; ++g) {
    const f32x4 va = *(const f32x4*)(v_buf + (size_t)(g0 + g) * 1024 + c * 8);
    const f32x4 vb = *(const f32x4*)(v_buf + (size_t)(g0 + g) * 1024 + c * 8 + 4);
    vg[g][0]=va[0]; vg[g][1]=va[1]; vg[g][2]=va[2]; vg[g][3]=va[3];
    vg[g][4]=vb[0]; vg[g][5]=vb[1]; vg[g][6]=vb[2]; vg[g][7]=vb[3];
  }
  const float* wc = W_coef + (size_t)c * 1088 + dh;
  f32x4 acc[4] = {{0,0,0,0},{0,0,0,0},{0,0,0,0},{0,0,0,0}};
  for (int dp = 0; dp < 128; ++dp) {
    const f32x4 w4 = *(const f32x4*)(wc + (size_t)dp * 8);
#pragma unroll
    for (int g = 0; g < 4; ++g) acc[g] += p_lds[g][dp] * w4;
  }
#pragma unroll
  for (int q = 0; q < 8; ++q) {
    const f32x4 w4 = *(const f32x4*)(wc + (size_t)(128 + q) * 8);
#pragma unroll
    for (int g = 0; g < 4; ++g) acc[g] += vg[g][q] * w4;
  }
#pragma unroll
  for (int g = 0; g < 4; ++g)
    *(f32x4*)(coef_buf + (size_t)(g0 + g) * 1024 + c * 8 + dh) = acc[g];
}

// ---------------- b += sum_t e * (sum_d W * coef)  (512 thr, h-partitioned) ----------------
__global__ __launch_bounds__(512) void bupd_kernel(
    const float* __restrict__ coef_buf, const float* __restrict__ e_buf,
    const float* __restrict__ W, float* __restrict__ b_state)
{
  __shared__ float e_lds[4][128][4];
  const int g0 = blockIdx.x * 4;
  const int tid = threadIdx.x;
  for (int i = tid; i < 2048; i += 512) ((float*)e_lds)[i] = e_buf[(size_t)g0 * 512 + i];
  __syncthreads();
  const int half = tid >> 8;
  const int t8 = tid & 255;
  const int c = t8 >> 1, dh = (t8 & 1) * 4;
  f32x4 cf[4];
#pragma unroll
  for (int g = 0; g < 4; ++g)
    cf[g] = *(const f32x4*)(coef_buf + (size_t)(g0 + g) * 1024 + c * 8 + dh);
  const int hbeg = half * 64, hend = hbeg + 64;
  for (int h = hbeg; h < hend; ++h) {
    float accg[4] = {0.f, 0.f, 0.f, 0.f};
#pragma unroll
    for (int t4 = 0; t4 < 4; ++t4) {
      const f32x4 w4 = *(const f32x4*)(W + ((size_t)(h * 4 + t4) * 128 + c) * 8 + dh);
#pragma unroll
      for (int g = 0; g < 4; ++g) {
        const float d4 = w4[0]*cf[g][0] + w4[1]*cf[g][1] + w4[2]*cf[g][2] + w4[3]*cf[g][3];
        accg[g] += e_lds[g][h][t4] * d4;
      }
    }
#pragma unroll
    for (int g = 0; g < 4; ++g) {
      const float full = accg[g] + __shfl_xor(accg[g], 1);
      if ((tid & 1) == 0)
        b_state[(size_t)(g0 + g) * 16384 + h * 128 + c] += full;
    }
  }
}

extern "C" void kernel_launch(void* const* d_in, const int* in_sizes, int n_in,
                              void* d_out, int out_size, void* d_ws, size_t ws_size,
                              hipStream_t stream) {
  const int* seq0 = (const int*)d_in[0];
  const int* seq1 = (const int*)d_in[1];
  const int* seq2 = (const int*)d_in[2];
  const int* seq3 = (const int*)d_in[3];
  const float* item_emb = (const float*)d_in[4];
  const float* Wih = (const float*)d_in[5];
  const float* Whh = (const float*)d_in[6];
  const float* bih = (const float*)d_in[7];
  const float* bhh = (const float*)d_in[8];
  const float* W = (const float*)d_in[9];
  const float* w_scale = (const float*)d_in[10];
  const float* bias_vec = (const float*)d_in[11];
  const float* alpha = (const float*)d_in[12];
  const float* W_coef = (const float*)d_in[13];
  float* out = (float*)d_out;

  char* ws = (char*)d_ws;
  float* e_buf    = (float*)(ws);                 // 1,048,576 B
  float* b_state  = (float*)(ws + 1048576);       // 33,554,432 B
  float* v_buf    = (float*)(ws + 34603008);      // 2,097,152 B
  float* vn_buf   = (float*)(ws + 36700160);      // 262,144 B
  float* p_buf    = (float*)(ws + 36962304);      // 262,144 B
  float* coef_buf = (float*)(ws + 37224448);      // 2,097,152 B
  float* row_m    = (float*)(ws + 39321600);      // 2,048 B
  float* row_inv  = (float*)(ws + 39323648);      // 2,048 B
  short* Ebf      = (short*)(ws + 39325696);      // 12,800,256 B
  short* Et       = (short*)(ws + 52125952);      // 12,812,288 B  (total ~64.9 MB)

  // gi scratch: t50 behaviors (59.0 MB) overlaps [b_state..Et) -- lifetime ends
  // before cast_ebf/build_et/memset below. click gi (78.6 MB) lives in d_out.
  unsigned short* gi_t50   = (unsigned short*)(ws + 1048576);
  unsigned short* gi_click = (unsigned short*)d_out;

  gi_gemm_kernel<<<dim3(700), 512, 0, stream>>>(seq0, seq1, seq2, seq3, item_emb, Wih,
                                                gi_t50, gi_click);
  gru_rec2_kernel<<<dim3(128), 512, 0, stream>>>(Whh, bih, bhh, gi_t50, gi_click, e_buf);
  cast_ebf<<<dim3(25001), 256, 0, stream>>>(item_emb, Ebf);
  build_et<<<dim3(782), 256, 0, stream>>>(item_emb, Et);
  hipMemsetAsync(b_state, 0, 33554432, stream);
  for (int it = 0; it < 2; ++it) {
    caps_v_kernel<<<dim3(128), 512, 0, stream>>>(b_state, e_buf, W, w_scale, bias_vec,
                                                 alpha, v_buf, vn_buf);
    logits_kernel<<<dim3(782, 4), 512, 0, stream>>>(vn_buf, Ebf, out);
    rowstats_kernel<<<dim3(512), 256, 0, stream>>>(out, row_m, row_inv);
    hipMemsetAsync(p_buf, 0, 262144, stream);
    pgemm_kernel<<<dim3(49, 8), 256, 0, stream>>>(out, Et, row_m, row_inv, p_buf);
    coef_kernel<<<dim3(128), 256, 0, stream>>>(p_buf, v_buf, W_coef, coef_buf);
    bupd_kernel<<<dim3(128), 512, 0, stream>>>(coef_buf, e_buf, W, b_state);
  }
  caps_v_kernel<<<dim3(128), 512, 0, stream>>>(b_state, e_buf, W, w_scale, bias_vec,
                                               alpha, v_buf, vn_buf);
  logits_kernel<<<dim3(782, 4), 512, 0, stream>>>(vn_buf, Ebf, out);
}

// Round 5
// 1348.601 us; speedup vs baseline: 1.0234x; 1.0234x over previous
//
#include <hip/hip_runtime.h>
#include <math.h>

typedef __attribute__((ext_vector_type(8))) short bf16x8;
typedef __attribute__((ext_vector_type(4))) float f32x4;
typedef __attribute__((ext_vector_type(4))) unsigned short u16x4;

static __device__ __forceinline__ short f2bf(float f) {
  unsigned u = __builtin_bit_cast(unsigned, f);
  u += 0x7fffu + ((u >> 16) & 1u);
  return (short)(u >> 16);
}
static __device__ __forceinline__ float bf2f(unsigned short s) {
  unsigned u = ((unsigned)s) << 16;
  return __builtin_bit_cast(float, u);
}
static __device__ __forceinline__ f32x4 mfma16(bf16x8 a, bf16x8 b, f32x4 c) {
  return __builtin_amdgcn_mfma_f32_16x16x32_bf16(a, b, c, 0, 0, 0);
}
static __device__ __forceinline__ bf16x8 pack8v(f32x4 a, f32x4 b) {
  bf16x8 r;
  r[0]=f2bf(a[0]); r[1]=f2bf(a[1]); r[2]=f2bf(a[2]); r[3]=f2bf(a[3]);
  r[4]=f2bf(b[0]); r[5]=f2bf(b[1]); r[6]=f2bf(b[2]); r[7]=f2bf(b[3]);
  return r;
}

// LDS-only barrier: does NOT drain vmcnt, so global prefetch stays in flight.
#define LGKM_BARRIER() do {                                   \
    asm volatile("s_waitcnt lgkmcnt(0)" ::: "memory");        \
    __builtin_amdgcn_s_barrier();                             \
    __builtin_amdgcn_sched_barrier(0);                        \
  } while (0)

// ---------------- cast item_emb -> bf16 (row-major) ----------------
__global__ __launch_bounds__(256) void cast_ebf(const float* __restrict__ E, short* __restrict__ Ebf) {
  int i = blockIdx.x * 256 + threadIdx.x;
  if (i < 50001 * 128) Ebf[i] = f2bf(E[i]);
}

// ---------------- build E^T bf16 [128][50048] (zero-padded) ----------------
__global__ __launch_bounds__(256) void build_et(const float* __restrict__ E, short* __restrict__ Et) {
  __shared__ float tile[64][132];
  const int v0 = blockIdx.x * 64;
  const int tid = threadIdx.x;
  const int r = tid >> 2, ks = (tid & 3) * 32;
  const int v = v0 + r;
  for (int j = 0; j < 32; j += 4) {
    f32x4 x = {0.f, 0.f, 0.f, 0.f};
    if (v < 50001) x = *(const f32x4*)(E + (size_t)v * 128 + ks + j);
    *(f32x4*)&tile[r][ks + j] = x;
  }
  __syncthreads();
  const int k = tid >> 1, vs = (tid & 1) * 32;
  for (int j = 0; j < 32; ++j)
    Et[(size_t)k * 50048 + v0 + vs + j] = f2bf(tile[vs + j][k]);
}

// ---------------- gi = x @ Wih^T for all (row, t): parallel gather + MFMA ----------------
// gi tile layout: per tile (16 batch rows at one t): [gate(3)][col(128)][row(16)] bf16 (6144 ushorts)
__global__ __launch_bounds__(512) void gi_gemm_kernel(
    const int* __restrict__ seq0, const int* __restrict__ seq1,
    const int* __restrict__ seq2, const int* __restrict__ seq3,
    const float* __restrict__ item_emb, const float* __restrict__ Wih,
    unsigned short* __restrict__ gi_t50, unsigned short* __restrict__ gi_click)
{
  const int b = blockIdx.x;           // 700 blocks, 16 tiles each
  int beh, tile0;
  if (b < 100)      { beh = 0; tile0 = b * 16; }
  else if (b < 200) { beh = 1; tile0 = (b - 100) * 16; }
  else if (b < 300) { beh = 2; tile0 = (b - 200) * 16; }
  else              { beh = 3; tile0 = (b - 300) * 16; }
  const int T = (beh == 3) ? 200 : 50;
  const int* seq = (beh == 0) ? seq0 : (beh == 1) ? seq1 : (beh == 2) ? seq2 : seq3;
  unsigned short* gibase = (beh == 3) ? gi_click : (gi_t50 + (size_t)beh * 1600 * 6144);

  const int tid = threadIdx.x;
  const int wave = tid >> 6, lane = tid & 63, lrow = lane & 15, lk8 = lane >> 4;
  const int bcol = wave * 16 + lrow;

  bf16x8 wif[3][4];
  const float* WihB = Wih + (size_t)beh * 384 * 128;
#pragma unroll
  for (int g = 0; g < 3; ++g) {
    const int wr = g * 128 + bcol;
#pragma unroll
    for (int kt = 0; kt < 4; ++kt) {
      const int k0 = kt * 32 + lk8 * 8;
      f32x4 a0 = *(const f32x4*)(WihB + (size_t)wr * 128 + k0);
      f32x4 a1 = *(const f32x4*)(WihB + (size_t)wr * 128 + k0 + 4);
      wif[g][kt] = pack8v(a0, a1);
    }
  }

  __shared__ short xt[16][132];
  const int gj = tid >> 5;
  const int gc = (tid & 31) * 4;

  for (int ti = 0; ti < 16; ++ti) {
    const int tile = tile0 + ti;
    const int r0blk = tile / T;
    const int t = tile - r0blk * T;
    {
      const int sidx = seq[(size_t)(r0blk * 16 + gj) * T + t];
      const f32x4 xv = *(const f32x4*)(item_emb + (size_t)sidx * 128 + gc);
      xt[gj][gc]     = f2bf(xv[0]);
      xt[gj][gc + 1] = f2bf(xv[1]);
      xt[gj][gc + 2] = f2bf(xv[2]);
      xt[gj][gc + 3] = f2bf(xv[3]);
    }
    __syncthreads();
    bf16x8 ax[4];
#pragma unroll
    for (int kt = 0; kt < 4; ++kt)
      ax[kt] = *(const bf16x8*)&xt[lrow][kt * 32 + lk8 * 8];
    f32x4 acc[3] = {{0,0,0,0},{0,0,0,0},{0,0,0,0}};
#pragma unroll
    for (int kt = 0; kt < 4; ++kt) {
      acc[0] = mfma16(ax[kt], wif[0][kt], acc[0]);
      acc[1] = mfma16(ax[kt], wif[1][kt], acc[1]);
      acc[2] = mfma16(ax[kt], wif[2][kt], acc[2]);
    }
    unsigned short* dst = gibase + (size_t)tile * 6144 + ((size_t)bcol * 16 + lk8 * 4);
#pragma unroll
    for (int g = 0; g < 3; ++g) {
      u16x4 o;
      o[0] = (unsigned short)f2bf(acc[g][0]);
      o[1] = (unsigned short)f2bf(acc[g][1]);
      o[2] = (unsigned short)f2bf(acc[g][2]);
      o[3] = (unsigned short)f2bf(acc[g][3]);
      *(u16x4*)(dst + (size_t)g * 2048) = o;
    }
    __syncthreads();
  }
}

// ---------------- GRU recurrence: lgkm-only barriers + 5-step reg prefetch of gi ----------------
__global__ __launch_bounds__(512, 2) void gru_rec2_kernel(
    const float* __restrict__ Whh, const float* __restrict__ bih,
    const float* __restrict__ bhh,
    const unsigned short* __restrict__ gi_t50,
    const unsigned short* __restrict__ gi_click,
    float* __restrict__ e_out)
{
  const int beh = blockIdx.x >> 5;
  const int r0blk = blockIdx.x & 31;
  const int r0 = r0blk * 16;
  const int T = (beh == 3) ? 200 : 50;
  const unsigned short* gib =
      ((beh == 3) ? gi_click : (gi_t50 + (size_t)beh * 1600 * 6144)) + (size_t)r0blk * T * 6144;

  const int tid = threadIdx.x;
  const int wave = tid >> 6;
  const int lane = tid & 63;
  const int lrow = lane & 15;
  const int lk8 = lane >> 4;
  const int bcol = wave * 16 + lrow;

  __shared__ short h0[16][140];
  __shared__ short h1[16][140];

  bf16x8 whf[3][4];
  const float* WhhB = Whh + (size_t)beh * 384 * 128;
#pragma unroll
  for (int g = 0; g < 3; ++g) {
    const int wr = g * 128 + bcol;
#pragma unroll
    for (int kt = 0; kt < 4; ++kt) {
      const int k0 = kt * 32 + lk8 * 8;
      f32x4 b0 = *(const f32x4*)(WhhB + (size_t)wr * 128 + k0);
      f32x4 b1 = *(const f32x4*)(WhhB + (size_t)wr * 128 + k0 + 4);
      whf[g][kt] = pack8v(b0, b1);
    }
  }
  const float bir = bih[beh * 384 + bcol];
  const float biz = bih[beh * 384 + 128 + bcol];
  const float bin_ = bih[beh * 384 + 256 + bcol];
  const float bhr = bhh[beh * 384 + bcol];
  const float bhz = bhh[beh * 384 + 128 + bcol];
  const float bhn = bhh[beh * 384 + 256 + bcol];

  for (int i = tid; i < 16 * 140; i += 512) ((short*)h0)[i] = 0;
  float hreg[4] = {0.f, 0.f, 0.f, 0.f};
  __syncthreads();

  const unsigned short* gip = gib + ((size_t)bcol * 16 + lk8 * 4);

  // ping-pong register chunks: 5 steps x 3 gates each (static indexing only)
  u16x4 ga[15], gb[15];

#define LOAD_CHUNK(BUF, C0) do {                                              \
    const unsigned short* _p = gip + (size_t)(C0) * 6144;                     \
    _Pragma("unroll")                                                         \
    for (int _s = 0; _s < 5; ++_s) {                                          \
      _Pragma("unroll")                                                       \
      for (int _g = 0; _g < 3; ++_g)                                          \
        BUF[_s * 3 + _g] = *(const u16x4*)(_p + (size_t)_s * 6144 + (size_t)_g * 2048); \
    }                                                                         \
  } while (0)

  short (*hin)[140] = h0;
  short (*hout)[140] = h1;

#define STEP(BUF, S) do {                                                     \
    bf16x8 ah[4];                                                             \
    _Pragma("unroll")                                                         \
    for (int kt = 0; kt < 4; ++kt)                                            \
      ah[kt] = *(const bf16x8*)&hin[lrow][kt * 32 + lk8 * 8];                 \
    f32x4 hr = {0,0,0,0}, hz = {0,0,0,0}, hn = {0,0,0,0};                     \
    _Pragma("unroll")                                                         \
    for (int kt = 0; kt < 4; ++kt) {                                          \
      hr = mfma16(ah[kt], whf[0][kt], hr);                                    \
      hz = mfma16(ah[kt], whf[1][kt], hz);                                    \
      hn = mfma16(ah[kt], whf[2][kt], hn);                                    \
    }                                                                         \
    const u16x4 gc0 = BUF[(S) * 3 + 0];                                       \
    const u16x4 gc1 = BUF[(S) * 3 + 1];                                       \
    const u16x4 gc2 = BUF[(S) * 3 + 2];                                       \
    _Pragma("unroll")                                                         \
    for (int e2 = 0; e2 < 4; ++e2) {                                          \
      const float rr = __fdividef(1.f, 1.f + __expf(-(bf2f(gc0[e2]) + bir + hr[e2] + bhr))); \
      const float zz = __fdividef(1.f, 1.f + __expf(-(bf2f(gc1[e2]) + biz + hz[e2] + bhz))); \
      const float ty = __expf(-2.f * (bf2f(gc2[e2]) + bin_ + rr * (hn[e2] + bhn)));          \
      const float nn = __fdividef(1.f - ty, 1.f + ty);                        \
      hreg[e2] = (1.f - zz) * nn + zz * hreg[e2];                             \
      hout[lk8 * 4 + e2][bcol] = f2bf(hreg[e2]);                              \
    }                                                                         \
    LGKM_BARRIER();                                                           \
    short (*_tmp)[140] = hin; hin = hout; hout = _tmp;                        \
  } while (0)

  LOAD_CHUNK(ga, 0);
  for (int c = 0; c < T; c += 10) {
    if (c + 5 < T) LOAD_CHUNK(gb, c + 5);
    STEP(ga, 0); STEP(ga, 1); STEP(ga, 2); STEP(ga, 3); STEP(ga, 4);
    if (c + 10 < T) LOAD_CHUNK(ga, c + 10);
    STEP(gb, 0); STEP(gb, 1); STEP(gb, 2); STEP(gb, 3); STEP(gb, 4);
  }
#undef STEP
#undef LOAD_CHUNK

#pragma unroll
  for (int e2 = 0; e2 < 4; ++e2)
    e_out[(size_t)(r0 + lk8 * 4 + e2) * 512 + bcol * 4 + beh] = hreg[e2];
}

// ---------------- caps: c = softmax(b), v = alpha * sum_h c*u, v_ = ||v||*ws+bias (512 thr, h-split) ----------------
__global__ __launch_bounds__(512) void caps_v_kernel(
    const float* __restrict__ b_state, const float* __restrict__ e_buf,
    const float* __restrict__ W, const float* __restrict__ w_scale,
    const float* __restrict__ bias_vec, const float* __restrict__ alpha,
    float* __restrict__ v_buf, float* __restrict__ vn_buf)
{
  __shared__ float e_lds[4][128][4];
  __shared__ float stat_m[4][128];
  __shared__ float stat_i[4][128];
  __shared__ float red[256][4][4];
  const int g0 = blockIdx.x * 4;
  const int tid = threadIdx.x;
  for (int i = tid; i < 2048; i += 512) ((float*)e_lds)[i] = e_buf[(size_t)g0 * 512 + i];
  const int wv = tid >> 6, ln = tid & 63;
  for (int ri = wv; ri < 512; ri += 8) {
    const int g = ri >> 7, h = ri & 127;
    const float* row = b_state + (size_t)(g0 + g) * 16384 + h * 128;
    const float x0 = row[ln], x1 = row[ln + 64];
    float m = fmaxf(x0, x1);
#pragma unroll
    for (int off = 32; off > 0; off >>= 1) m = fmaxf(m, __shfl_xor(m, off));
    float s = __expf(x0 - m) + __expf(x1 - m);
#pragma unroll
    for (int off = 32; off > 0; off >>= 1) s += __shfl_xor(s, off);
    if (ln == 0) { stat_m[g][h] = m; stat_i[g][h] = 1.f / s; }
  }
  __syncthreads();
  const int half = tid >> 8;
  const int t8 = tid & 255;
  const int c = t8 >> 1, dh = (t8 & 1) * 4;
  f32x4 acc[4] = {{0,0,0,0},{0,0,0,0},{0,0,0,0},{0,0,0,0}};
  const int hbeg = half * 64, hend = hbeg + 64;
  for (int h = hbeg; h < hend; ++h) {
    float cv[4];
#pragma unroll
    for (int g = 0; g < 4; ++g)
      cv[g] = __expf(b_state[(size_t)(g0 + g) * 16384 + h * 128 + c] - stat_m[g][h]) * stat_i[g][h];
#pragma unroll
    for (int t4 = 0; t4 < 4; ++t4) {
      const f32x4 w4 = *(const f32x4*)(W + ((size_t)(h * 4 + t4) * 128 + c) * 8 + dh);
#pragma unroll
      for (int g = 0; g < 4; ++g) acc[g] += (cv[g] * e_lds[g][h][t4]) * w4;
    }
  }
  if (half == 1) {
#pragma unroll
    for (int g = 0; g < 4; ++g) *(f32x4*)&red[t8][g][0] = acc[g];
  }
  __syncthreads();
  if (half == 0) {
    const float al = alpha[0];
#pragma unroll
    for (int g = 0; g < 4; ++g) {
      acc[g] = (acc[g] + *(const f32x4*)&red[t8][g][0]) * al;
      *(f32x4*)(v_buf + (size_t)(g0 + g) * 1024 + c * 8 + dh) = acc[g];
      float ss = acc[g][0]*acc[g][0] + acc[g][1]*acc[g][1] + acc[g][2]*acc[g][2] + acc[g][3]*acc[g][3];
      ss += __shfl_xor(ss, 1);
      if ((tid & 1) == 0) vn_buf[(g0 + g) * 128 + c] = sqrtf(ss) * w_scale[c] + bias_vec[c];
    }
  }
}

// ---------------- logits = vn @ E^T (MFMA bf16), into d_out ----------------
__global__ __launch_bounds__(512) void logits_kernel(
    const float* __restrict__ vn, const short* __restrict__ Ebf,
    float* __restrict__ out)
{
  __shared__ short et[64][136];
  const int n0 = blockIdx.x * 64;
  const int m0 = blockIdx.y * 128;
  const int tid = threadIdx.x;
  const int wave = tid >> 6, lane = tid & 63, lrow = lane & 15, lk8 = lane >> 4;
  {
    const int r = tid >> 3, ks = (tid & 7) * 16;
    const int v = n0 + r;
    bf16x8 a = {0,0,0,0,0,0,0,0}, b = {0,0,0,0,0,0,0,0};
    if (v < 50001) {
      a = *(const bf16x8*)(Ebf + (size_t)v * 128 + ks);
      b = *(const bf16x8*)(Ebf + (size_t)v * 128 + ks + 8);
    }
    *(bf16x8*)&et[r][ks] = a;
    *(bf16x8*)&et[r][ks + 8] = b;
  }
  __syncthreads();
  const int arow = m0 + wave * 16 + lrow;
  bf16x8 afr[4];
#pragma unroll
  for (int kt = 0; kt < 4; ++kt) {
    const float* p = vn + (size_t)arow * 128 + kt * 32 + lk8 * 8;
    afr[kt] = pack8v(*(const f32x4*)p, *(const f32x4*)(p + 4));
  }
  f32x4 acc[4] = {{0,0,0,0},{0,0,0,0},{0,0,0,0},{0,0,0,0}};
#pragma unroll
  for (int kt = 0; kt < 4; ++kt) {
#pragma unroll
    for (int nt = 0; nt < 4; ++nt) {
      const bf16x8 bfr = *(const bf16x8*)&et[nt * 16 + lrow][kt * 32 + lk8 * 8];
      acc[nt] = mfma16(afr[kt], bfr, acc[nt]);
    }
  }
#pragma unroll
  for (int nt = 0; nt < 4; ++nt) {
    const int col = n0 + nt * 16 + lrow;
    if (col < 50001) {
      const int row = m0 + wave * 16 + lk8 * 4;
#pragma unroll
      for (int e2 = 0; e2 < 4; ++e2)
        out[(size_t)(row + e2) * 50001 + col] = acc[nt][e2];
    }
  }
}

// ---------------- per-row softmax stats over 50001 logits ----------------
__global__ __launch_bounds__(256) void rowstats_kernel(
    const float* __restrict__ out, float* __restrict__ row_m, float* __restrict__ row_inv)
{
  const int b = blockIdx.x;
  const int tid = threadIdx.x;
  const float* row = out + (size_t)b * 50001;
  float m = -1e30f, s = 0.f;
  for (int i = tid; i < 50001; i += 256) {
    const float x = row[i];
    const float nm = fmaxf(m, x);
    s = s * __expf(m - nm) + __expf(x - nm);
    m = nm;
  }
#pragma unroll
  for (int off = 32; off > 0; off >>= 1) {
    const float m2 = __shfl_xor(m, off), s2 = __shfl_xor(s, off);
    const float nm = fmaxf(m, m2);
    s = s * __expf(m - nm) + s2 * __expf(m2 - nm);
    m = nm;
  }
  __shared__ float ms[4], ss[4];
  const int wv = tid >> 6, ln = tid & 63;
  if (ln == 0) { ms[wv] = m; ss[wv] = s; }
  __syncthreads();
  if (tid == 0) {
    float M = ms[0], S = ss[0];
    for (int w = 1; w < 4; ++w) {
      const float nm = fmaxf(M, ms[w]);
      S = S * __expf(M - nm) + ss[w] * __expf(ms[w] - nm);
      M = nm;
    }
    row_m[b] = M;
    row_inv[b] = 1.f / S;
  }
}

// ---------------- p = softmax(logits) @ E  (split-K MFMA, atomic accumulate) ----------------
__global__ __launch_bounds__(256) void pgemm_kernel(
    const float* __restrict__ out, const short* __restrict__ Et,
    const float* __restrict__ row_m, const float* __restrict__ row_inv,
    float* __restrict__ p_buf)
{
  const int tid = threadIdx.x;
  const int wave = tid >> 6, lane = tid & 63, lrow = lane & 15, lk8 = lane >> 4;
  const int m0 = blockIdx.y * 64;
  const int row = m0 + wave * 16 + lrow;
  const float rm = row_m[row], ri = row_inv[row];
  const float* lp = out + (size_t)row * 50001;
  const int kbeg = blockIdx.x * 1024;
  f32x4 acc[8] = {{0,0,0,0},{0,0,0,0},{0,0,0,0},{0,0,0,0},
                  {0,0,0,0},{0,0,0,0},{0,0,0,0},{0,0,0,0}};
  if (kbeg + 1024 <= 50001) {
    for (int v0 = kbeg; v0 < kbeg + 1024; v0 += 32) {
      const int kb = v0 + lk8 * 8;
      float x[8];
      __builtin_memcpy(x, lp + kb, 32);
      bf16x8 afr;
#pragma unroll
      for (int j = 0; j < 8; ++j) afr[j] = f2bf(__expf(x[j] - rm) * ri);
#pragma unroll
      for (int nt = 0; nt < 8; ++nt) {
        const bf16x8 bfr = *(const bf16x8*)(Et + (size_t)(nt * 16 + lrow) * 50048 + kb);
        acc[nt] = mfma16(afr, bfr, acc[nt]);
      }
    }
  } else {
    const int kend = 50001;
    for (int v0 = kbeg; v0 < kend; v0 += 32) {
      const int kb = v0 + lk8 * 8;
      float x[8];
#pragma unroll
      for (int j = 0; j < 8; ++j) x[j] = (kb + j < 50001) ? lp[kb + j] : rm - 100.f;
      bf16x8 afr;
#pragma unroll
      for (int j = 0; j < 8; ++j) afr[j] = f2bf(__expf(x[j] - rm) * ri);
#pragma unroll
      for (int nt = 0; nt < 8; ++nt) {
        const bf16x8 bfr = *(const bf16x8*)(Et + (size_t)(nt * 16 + lrow) * 50048 + kb);
        acc[nt] = mfma16(afr, bfr, acc[nt]);
      }
    }
  }
#pragma unroll
  for (int nt = 0; nt < 8; ++nt)
#pragma unroll
    for (int e2 = 0; e2 < 4; ++e2)
      atomicAdd(&p_buf[(size_t)(m0 + wave * 16 + lk8 * 4 + e2) * 128 + nt * 16 + lrow], acc[nt][e2]);
}

// ---------------- coef = concat(p, v) @ W_coef ----------------
__global__ __launch_bounds__(256) void coef_kernel(
    const float* __restrict__ p_buf, const float* __restrict__ v_buf,
    const float* __restrict__ W_coef, float* __restrict__ coef_buf)
{
  __shared__ float p_lds[4][128];
  const int g0 = blockIdx.x * 4;
  const int tid = threadIdx.x;
  for (int i = tid; i < 512; i += 256) ((float*)p_lds)[i] = p_buf[(size_t)g0 * 128 + i];
  __syncthreads();
  const int c = tid >> 1, dh = (tid & 1) * 4;
  float vg[4][8];
#pragma unroll
  for (int g = 0; g < 4; ++g) {
    const f32x4 va = *(const f32x4*)(v_buf + (size_t)(g0 + g) * 1024 + c * 8);
    const f32x4 vb = *(const f32x4*)(v_buf + (size_t)(g0 + g) * 1024 + c * 8 + 4);
    vg[g][0]=va[0]; vg[g][1]=va[1]; vg[g][2]=va[2]; vg[g][3]=va[3];
    vg[g][4]=vb[0]; vg[g][5]=vb[1]; vg[g][6]=vb[2]; vg[g][7]=vb[3];
  }
  const float* wc = W_coef + (size_t)c * 1088 + dh;
  f32x4 acc[4] = {{0,0,0,0},{0,0,0,0},{0,0,0,0},{0,0,0,0}};
  for (int dp = 0; dp < 128; ++dp) {
    const f32x4 w4 = *(const f32x4*)(wc + (size_t)dp * 8);
#pragma unroll
    for (int g = 0; g < 4; ++g) acc[g] += p_lds[g][dp] * w4;
  }
#pragma unroll
  for (int q = 0; q < 8; ++q) {
    const f32x4 w4 = *(const f32x4*)(wc + (size_t)(128 + q) * 8);
#pragma unroll
    for (int g = 0; g < 4; ++g) acc[g] += vg[g][q] * w4;
  }
#pragma unroll
  for (int g = 0; g < 4; ++g)
    *(f32x4*)(coef_buf + (size_t)(g0 + g) * 1024 + c * 8 + dh) = acc[g];
}

// ---------------- b += sum_t e * (sum_d W * coef)  (512 thr, h-partitioned) ----------------
__global__ __launch_bounds__(512) void bupd_kernel(
    const float* __restrict__ coef_buf, const float* __restrict__ e_buf,
    const float* __restrict__ W, float* __restrict__ b_state)
{
  __shared__ float e_lds[4][128][4];
  const int g0 = blockIdx.x * 4;
  const int tid = threadIdx.x;
  for (int i = tid; i < 2048; i += 512) ((float*)e_lds)[i] = e_buf[(size_t)g0 * 512 + i];
  __syncthreads();
  const int half = tid >> 8;
  const int t8 = tid & 255;
  const int c = t8 >> 1, dh = (t8 & 1) * 4;
  f32x4 cf[4];
#pragma unroll
  for (int g = 0; g < 4; ++g)
    cf[g] = *(const f32x4*)(coef_buf + (size_t)(g0 + g) * 1024 + c * 8 + dh);
  const int hbeg = half * 64, hend = hbeg + 64;
  for (int h = hbeg; h < hend; ++h) {
    float accg[4] = {0.f, 0.f, 0.f, 0.f};
#pragma unroll
    for (int t4 = 0; t4 < 4; ++t4) {
      const f32x4 w4 = *(const f32x4*)(W + ((size_t)(h * 4 + t4) * 128 + c) * 8 + dh);
#pragma unroll
      for (int g = 0; g < 4; ++g) {
        const float d4 = w4[0]*cf[g][0] + w4[1]*cf[g][1] + w4[2]*cf[g][2] + w4[3]*cf[g][3];
        accg[g] += e_lds[g][h][t4] * d4;
      }
    }
#pragma unroll
    for (int g = 0; g < 4; ++g) {
      const float full = accg[g] + __shfl_xor(accg[g], 1);
      if ((tid & 1) == 0)
        b_state[(size_t)(g0 + g) * 16384 + h * 128 + c] += full;
    }
  }
}

extern "C" void kernel_launch(void* const* d_in, const int* in_sizes, int n_in,
                              void* d_out, int out_size, void* d_ws, size_t ws_size,
                              hipStream_t stream) {
  const int* seq0 = (const int*)d_in[0];
  const int* seq1 = (const int*)d_in[1];
  const int* seq2 = (const int*)d_in[2];
  const int* seq3 = (const int*)d_in[3];
  const float* item_emb = (const float*)d_in[4];
  const float* Wih = (const float*)d_in[5];
  const float* Whh = (const float*)d_in[6];
  const float* bih = (const float*)d_in[7];
  const float* bhh = (const float*)d_in[8];
  const float* W = (const float*)d_in[9];
  const float* w_scale = (const float*)d_in[10];
  const float* bias_vec = (const float*)d_in[11];
  const float* alpha = (const float*)d_in[12];
  const float* W_coef = (const float*)d_in[13];
  float* out = (float*)d_out;

  char* ws = (char*)d_ws;
  float* e_buf    = (float*)(ws);                 // 1,048,576 B
  float* b_state  = (float*)(ws + 1048576);       // 33,554,432 B
  float* v_buf    = (float*)(ws + 34603008);      // 2,097,152 B
  float* vn_buf   = (float*)(ws + 36700160);      // 262,144 B
  float* p_buf    = (float*)(ws + 36962304);      // 262,144 B
  float* coef_buf = (float*)(ws + 37224448);      // 2,097,152 B
  float* row_m    = (float*)(ws + 39321600);      // 2,048 B
  float* row_inv  = (float*)(ws + 39323648);      // 2,048 B
  short* Ebf      = (short*)(ws + 39325696);      // 12,800,256 B
  short* Et       = (short*)(ws + 52125952);      // 12,812,288 B  (total ~64.9 MB)

  // gi scratch: t50 behaviors (59.0 MB) overlaps [b_state..Et) -- lifetime ends
  // before cast_ebf/build_et/memset below. click gi (78.6 MB) lives in d_out.
  unsigned short* gi_t50   = (unsigned short*)(ws + 1048576);
  unsigned short* gi_click = (unsigned short*)d_out;

  gi_gemm_kernel<<<dim3(700), 512, 0, stream>>>(seq0, seq1, seq2, seq3, item_emb, Wih,
                                                gi_t50, gi_click);
  gru_rec2_kernel<<<dim3(128), 512, 0, stream>>>(Whh, bih, bhh, gi_t50, gi_click, e_buf);
  cast_ebf<<<dim3(25001), 256, 0, stream>>>(item_emb, Ebf);
  build_et<<<dim3(782), 256, 0, stream>>>(item_emb, Et);
  hipMemsetAsync(b_state, 0, 33554432, stream);
  for (int it = 0; it < 2; ++it) {
    caps_v_kernel<<<dim3(128), 512, 0, stream>>>(b_state, e_buf, W, w_scale, bias_vec,
                                                 alpha, v_buf, vn_buf);
    logits_kernel<<<dim3(782, 4), 512, 0, stream>>>(vn_buf, Ebf, out);
    rowstats_kernel<<<dim3(512), 256, 0, stream>>>(out, row_m, row_inv);
    hipMemsetAsync(p_buf, 0, 262144, stream);
    pgemm_kernel<<<dim3(49, 8), 256, 0, stream>>>(out, Et, row_m, row_inv, p_buf);
    coef_kernel<<<dim3(128), 256, 0, stream>>>(p_buf, v_buf, W_coef, coef_buf);
    bupd_kernel<<<dim3(128), 512, 0, stream>>>(coef_buf, e_buf, W, b_state);
  }
  caps_v_kernel<<<dim3(128), 512, 0, stream>>>(b_state, e_buf, W, w_scale, bias_vec,
                                               alpha, v_buf, vn_buf);
  logits_kernel<<<dim3(782, 4), 512, 0, stream>>>(vn_buf, Ebf, out);
}

// Round 6
// 1144.027 us; speedup vs baseline: 1.2064x; 1.1788x over previous
//
#include <hip/hip_runtime.h>
#include <math.h>

typedef __attribute__((ext_vector_type(8))) short bf16x8;
typedef __attribute__((ext_vector_type(4))) float f32x4;
typedef __attribute__((ext_vector_type(4))) unsigned short u16x4;
typedef __attribute__((ext_vector_type(2))) unsigned short u16x2;

static __device__ __forceinline__ short f2bf(float f) {
  unsigned u = __builtin_bit_cast(unsigned, f);
  u += 0x7fffu + ((u >> 16) & 1u);
  return (short)(u >> 16);
}
static __device__ __forceinline__ float bf2f(unsigned short s) {
  unsigned u = ((unsigned)s) << 16;
  return __builtin_bit_cast(float, u);
}
static __device__ __forceinline__ f32x4 mfma16(bf16x8 a, bf16x8 b, f32x4 c) {
  return __builtin_amdgcn_mfma_f32_16x16x32_bf16(a, b, c, 0, 0, 0);
}
static __device__ __forceinline__ bf16x8 pack8v(f32x4 a, f32x4 b) {
  bf16x8 r;
  r[0]=f2bf(a[0]); r[1]=f2bf(a[1]); r[2]=f2bf(a[2]); r[3]=f2bf(a[3]);
  r[4]=f2bf(b[0]); r[5]=f2bf(b[1]); r[6]=f2bf(b[2]); r[7]=f2bf(b[3]);
  return r;
}
static __device__ __forceinline__ float fastrcp(float x) {
  float r;
  asm("v_rcp_f32_e32 %0, %1" : "=v"(r) : "v"(x));
  return r;
}

// LDS-only barrier: does NOT drain vmcnt, global prefetch stays in flight.
#define LGKM_BARRIER() do {                                   \
    asm volatile("s_waitcnt lgkmcnt(0)" ::: "memory");        \
    __builtin_amdgcn_s_barrier();                             \
    __builtin_amdgcn_sched_barrier(0);                        \
  } while (0)

// ---------------- cast item_emb -> bf16 (row-major) ----------------
__global__ __launch_bounds__(256) void cast_ebf(const float* __restrict__ E, short* __restrict__ Ebf) {
  int i = blockIdx.x * 256 + threadIdx.x;
  if (i < 50001 * 128) Ebf[i] = f2bf(E[i]);
}

// ---------------- build E^T bf16 [128][50048] (zero-padded) ----------------
__global__ __launch_bounds__(256) void build_et(const float* __restrict__ E, short* __restrict__ Et) {
  __shared__ float tile[64][132];
  const int v0 = blockIdx.x * 64;
  const int tid = threadIdx.x;
  const int r = tid >> 2, ks = (tid & 3) * 32;
  const int v = v0 + r;
  for (int j = 0; j < 32; j += 4) {
    f32x4 x = {0.f, 0.f, 0.f, 0.f};
    if (v < 50001) x = *(const f32x4*)(E + (size_t)v * 128 + ks + j);
    *(f32x4*)&tile[r][ks + j] = x;
  }
  __syncthreads();
  const int k = tid >> 1, vs = (tid & 1) * 32;
  for (int j = 0; j < 32; ++j)
    Et[(size_t)k * 50048 + v0 + vs + j] = f2bf(tile[vs + j][k]);
}

// ---------------- gi = x @ Wih^T for all (row,t), stored as compact 8-row octet tiles ----------------
// octet tile (8 batch rows at one t): [gate(3)][col(128)][row(8)] ushort = 3072 ushorts (6 KB)
// click: base = gi_click + (oct*200 + t)*3072, oct 0..63
// t50:   base = gi_t50 + beh*9830400 + (oct*50 + t)*3072
__global__ __launch_bounds__(512) void gi_gemm_kernel(
    const int* __restrict__ seq0, const int* __restrict__ seq1,
    const int* __restrict__ seq2, const int* __restrict__ seq3,
    const float* __restrict__ item_emb, const float* __restrict__ Wih,
    unsigned short* __restrict__ gi_t50, unsigned short* __restrict__ gi_click)
{
  const int b = blockIdx.x;           // 700 blocks, 16 tiles (16-row) each
  int beh, tile0;
  if (b < 100)      { beh = 0; tile0 = b * 16; }
  else if (b < 200) { beh = 1; tile0 = (b - 100) * 16; }
  else if (b < 300) { beh = 2; tile0 = (b - 200) * 16; }
  else              { beh = 3; tile0 = (b - 300) * 16; }
  const int T = (beh == 3) ? 200 : 50;
  const int* seq = (beh == 0) ? seq0 : (beh == 1) ? seq1 : (beh == 2) ? seq2 : seq3;
  unsigned short* gibase = (beh == 3) ? gi_click : (gi_t50 + (size_t)beh * 9830400);

  const int tid = threadIdx.x;
  const int wave = tid >> 6, lane = tid & 63, lrow = lane & 15, lk8 = lane >> 4;
  const int bcol = wave * 16 + lrow;

  bf16x8 wif[3][4];
  const float* WihB = Wih + (size_t)beh * 384 * 128;
#pragma unroll
  for (int g = 0; g < 3; ++g) {
    const int wr = g * 128 + bcol;
#pragma unroll
    for (int kt = 0; kt < 4; ++kt) {
      const int k0 = kt * 32 + lk8 * 8;
      f32x4 a0 = *(const f32x4*)(WihB + (size_t)wr * 128 + k0);
      f32x4 a1 = *(const f32x4*)(WihB + (size_t)wr * 128 + k0 + 4);
      wif[g][kt] = pack8v(a0, a1);
    }
  }

  __shared__ short xt[16][132];
  const int gj = tid >> 5;
  const int gc = (tid & 31) * 4;

  for (int ti = 0; ti < 16; ++ti) {
    const int tile = tile0 + ti;
    const int r0blk = tile / T;         // 16-row group 0..31
    const int t = tile - r0blk * T;
    {
      const int sidx = seq[(size_t)(r0blk * 16 + gj) * T + t];
      const f32x4 xv = *(const f32x4*)(item_emb + (size_t)sidx * 128 + gc);
      xt[gj][gc]     = f2bf(xv[0]);
      xt[gj][gc + 1] = f2bf(xv[1]);
      xt[gj][gc + 2] = f2bf(xv[2]);
      xt[gj][gc + 3] = f2bf(xv[3]);
    }
    __syncthreads();
    bf16x8 ax[4];
#pragma unroll
    for (int kt = 0; kt < 4; ++kt)
      ax[kt] = *(const bf16x8*)&xt[lrow][kt * 32 + lk8 * 8];
    f32x4 acc[3] = {{0,0,0,0},{0,0,0,0},{0,0,0,0}};
#pragma unroll
    for (int kt = 0; kt < 4; ++kt) {
      acc[0] = mfma16(ax[kt], wif[0][kt], acc[0]);
      acc[1] = mfma16(ax[kt], wif[1][kt], acc[1]);
      acc[2] = mfma16(ax[kt], wif[2][kt], acc[2]);
    }
    // C rows lk8*4+e2 = batch rows; octet = 2*r0blk + (lk8>>1), row-in-oct = (lk8&1)*4+e2
    unsigned short* base = gibase + ((size_t)(2 * r0blk + (lk8 >> 1)) * T + t) * 3072;
    unsigned short* dst = base + bcol * 8 + (lk8 & 1) * 4;
#pragma unroll
    for (int g = 0; g < 3; ++g) {
      u16x4 o;
      o[0] = (unsigned short)f2bf(acc[g][0]);
      o[1] = (unsigned short)f2bf(acc[g][1]);
      o[2] = (unsigned short)f2bf(acc[g][2]);
      o[3] = (unsigned short)f2bf(acc[g][3]);
      *(u16x4*)(dst + g * 1024) = o;
    }
    __syncthreads();
  }
}

// ---------------- GRU recurrence: 8 rows/block, 256 blocks, epilogue e2 in {0,1} only ----------------
// batch row b (0..7) lives in MFMA M-slot (b>>1)*4 + (b&1)  ->  slot = lk8*4 + e2, b = lk8*2 + e2
__global__ __launch_bounds__(256, 1) void gru_rec3_kernel(
    const float* __restrict__ Whh, const float* __restrict__ bih,
    const float* __restrict__ bhh,
    const unsigned short* __restrict__ gi_t50,
    const unsigned short* __restrict__ gi_click,
    float* __restrict__ e_out)
{
  const int beh = blockIdx.x >> 6;      // 4 beh x 64 octets
  const int oct = blockIdx.x & 63;
  const int T = (beh == 3) ? 200 : 50;
  const unsigned short* gib =
      ((beh == 3) ? gi_click : (gi_t50 + (size_t)beh * 9830400)) + (size_t)oct * T * 3072;

  const int tid = threadIdx.x;
  const int w = tid >> 6;
  const int lane = tid & 63;
  const int lrow = lane & 15;
  const int lk8 = lane >> 4;
  const int col0 = w * 32 + lrow;       // ct=0
  const int col1 = col0 + 16;           // ct=1

  __shared__ short h0[16][140];
  __shared__ short h1[16][140];

  // Whh B-fragments: 3 gates x 2 col-tiles x 4 ktiles = 96 VGPR
  bf16x8 whf[3][2][4];
  const float* WhhB = Whh + (size_t)beh * 384 * 128;
#pragma unroll
  for (int g = 0; g < 3; ++g) {
#pragma unroll
    for (int ct = 0; ct < 2; ++ct) {
      const int wr = g * 128 + (ct ? col1 : col0);
#pragma unroll
      for (int kt = 0; kt < 4; ++kt) {
        const int k0 = kt * 32 + lk8 * 8;
        f32x4 b0 = *(const f32x4*)(WhhB + (size_t)wr * 128 + k0);
        f32x4 b1 = *(const f32x4*)(WhhB + (size_t)wr * 128 + k0 + 4);
        whf[g][ct][kt] = pack8v(b0, b1);
      }
    }
  }
  float bR[2], bZ[2], bN[2], bHN[2];
#pragma unroll
  for (int ct = 0; ct < 2; ++ct) {
    const int c = ct ? col1 : col0;
    bR[ct]  = bih[beh * 384 + c] + bhh[beh * 384 + c];
    bZ[ct]  = bih[beh * 384 + 128 + c] + bhh[beh * 384 + 128 + c];
    bN[ct]  = bih[beh * 384 + 256 + c];
    bHN[ct] = bhh[beh * 384 + 256 + c];
  }

  for (int i = tid; i < 16 * 140; i += 256) { ((short*)h0)[i] = 0; ((short*)h1)[i] = 0; }
  float hreg[4] = {0.f, 0.f, 0.f, 0.f};
  __syncthreads();

  // gi read offsets: per (ct,g): col*8 + lk8*2 within [gate*1024 + ...]
  const unsigned short* gp0 = gib + col0 * 8 + lk8 * 2;
  const unsigned short* gp1 = gib + col1 * 8 + lk8 * 2;

  u16x2 ga[30], gb[30];   // 5 steps x 2ct x 3g

#define LOAD_CHUNK(BUF, C0) do {                                              \
    _Pragma("unroll")                                                         \
    for (int _s = 0; _s < 5; ++_s) {                                          \
      const size_t _o = (size_t)((C0) + _s) * 3072;                           \
      _Pragma("unroll")                                                       \
      for (int _g = 0; _g < 3; ++_g) {                                        \
        BUF[_s * 6 + 0 * 3 + _g] = *(const u16x2*)(gp0 + _o + _g * 1024);     \
        BUF[_s * 6 + 1 * 3 + _g] = *(const u16x2*)(gp1 + _o + _g * 1024);     \
      }                                                                       \
    }                                                                         \
  } while (0)

  short (*hin)[140] = h0;
  short (*hout)[140] = h1;

#define STEP(BUF, S) do {                                                     \
    bf16x8 ah[4];                                                             \
    _Pragma("unroll")                                                         \
    for (int kt = 0; kt < 4; ++kt)                                            \
      ah[kt] = *(const bf16x8*)&hin[lrow][kt * 32 + lk8 * 8];                 \
    f32x4 hr_[2], hz_[2], hn_[2];                                             \
    _Pragma("unroll")                                                         \
    for (int ct = 0; ct < 2; ++ct) {                                          \
      hr_[ct] = (f32x4){0,0,0,0}; hz_[ct] = (f32x4){0,0,0,0}; hn_[ct] = (f32x4){0,0,0,0}; \
      _Pragma("unroll")                                                       \
      for (int kt = 0; kt < 4; ++kt) {                                        \
        hr_[ct] = mfma16(ah[kt], whf[0][ct][kt], hr_[ct]);                    \
        hz_[ct] = mfma16(ah[kt], whf[1][ct][kt], hz_[ct]);                    \
        hn_[ct] = mfma16(ah[kt], whf[2][ct][kt], hn_[ct]);                    \
      }                                                                       \
    }                                                                         \
    _Pragma("unroll")                                                         \
    for (int ct = 0; ct < 2; ++ct) {                                          \
      _Pragma("unroll")                                                       \
      for (int e2 = 0; e2 < 2; ++e2) {                                        \
        const float xr = bf2f(BUF[(S)*6 + ct*3 + 0][e2]) + bR[ct] + hr_[ct][e2]; \
        const float xz = bf2f(BUF[(S)*6 + ct*3 + 1][e2]) + bZ[ct] + hz_[ct][e2]; \
        const float ea = __expf(-xr);                                         \
        const float eb = __expf(-xz);                                         \
        const float pa = 1.f + ea, pb = 1.f + eb;                             \
        const float rd = fastrcp(pa * pb);                                    \
        const float rr = pb * rd;                                             \
        const float zz = pa * rd;                                             \
        const float tn = bf2f(BUF[(S)*6 + ct*3 + 2][e2]) + bN[ct] + rr * (hn_[ct][e2] + bHN[ct]); \
        const float tt = __expf(-2.f * tn);                                   \
        const float nn = (1.f - tt) * fastrcp(1.f + tt);                      \
        const int idx = ct * 2 + e2;                                          \
        hreg[idx] = nn + zz * (hreg[idx] - nn);                               \
        hout[lk8 * 4 + e2][ct ? col1 : col0] = f2bf(hreg[idx]);               \
      }                                                                       \
    }                                                                         \
    LGKM_BARRIER();                                                           \
    short (*_tmp)[140] = hin; hin = hout; hout = _tmp;                        \
  } while (0)

  LOAD_CHUNK(ga, 0);
  for (int c = 0; c < T; c += 10) {
    if (c + 5 < T) LOAD_CHUNK(gb, c + 5);
    STEP(ga, 0); STEP(ga, 1); STEP(ga, 2); STEP(ga, 3); STEP(ga, 4);
    if (c + 10 < T) LOAD_CHUNK(ga, c + 10);
    STEP(gb, 0); STEP(gb, 1); STEP(gb, 2); STEP(gb, 3); STEP(gb, 4);
  }
#undef STEP
#undef LOAD_CHUNK

#pragma unroll
  for (int ct = 0; ct < 2; ++ct)
#pragma unroll
    for (int e2 = 0; e2 < 2; ++e2)
      e_out[(size_t)(oct * 8 + lk8 * 2 + e2) * 512 + (ct ? col1 : col0) * 4 + beh] = hreg[ct * 2 + e2];
}

// ---------------- caps: c = softmax(b), v = alpha * sum_h c*u, v_ = ||v||*ws+bias ----------------
template<bool FIRST>
__global__ __launch_bounds__(512) void caps_v_kernel(
    const float* __restrict__ b_state, const float* __restrict__ e_buf,
    const float* __restrict__ W, const float* __restrict__ w_scale,
    const float* __restrict__ bias_vec, const float* __restrict__ alpha,
    float* __restrict__ v_buf, float* __restrict__ vn_buf)
{
  __shared__ float e_lds[4][128][4];
  __shared__ float stat_m[4][128];
  __shared__ float stat_i[4][128];
  __shared__ float red[256][4][4];
  const int g0 = blockIdx.x * 4;
  const int tid = threadIdx.x;
  for (int i = tid; i < 2048; i += 512) ((float*)e_lds)[i] = e_buf[(size_t)g0 * 512 + i];
  if (!FIRST) {
    const int wv = tid >> 6, ln = tid & 63;
    for (int ri = wv; ri < 512; ri += 8) {
      const int g = ri >> 7, h = ri & 127;
      const float* row = b_state + (size_t)(g0 + g) * 16384 + h * 128;
      const float x0 = row[ln], x1 = row[ln + 64];
      float m = fmaxf(x0, x1);
#pragma unroll
      for (int off = 32; off > 0; off >>= 1) m = fmaxf(m, __shfl_xor(m, off));
      float s = __expf(x0 - m) + __expf(x1 - m);
#pragma unroll
      for (int off = 32; off > 0; off >>= 1) s += __shfl_xor(s, off);
      if (ln == 0) { stat_m[g][h] = m; stat_i[g][h] = 1.f / s; }
    }
  }
  __syncthreads();
  const int half = tid >> 8;
  const int t8 = tid & 255;
  const int c = t8 >> 1, dh = (t8 & 1) * 4;
  f32x4 acc[4] = {{0,0,0,0},{0,0,0,0},{0,0,0,0},{0,0,0,0}};
  const int hbeg = half * 64, hend = hbeg + 64;
  for (int h = hbeg; h < hend; ++h) {
    float cv[4];
#pragma unroll
    for (int g = 0; g < 4; ++g)
      cv[g] = FIRST ? 0.0078125f
            : __expf(b_state[(size_t)(g0 + g) * 16384 + h * 128 + c] - stat_m[g][h]) * stat_i[g][h];
#pragma unroll
    for (int t4 = 0; t4 < 4; ++t4) {
      const f32x4 w4 = *(const f32x4*)(W + ((size_t)(h * 4 + t4) * 128 + c) * 8 + dh);
#pragma unroll
      for (int g = 0; g < 4; ++g) acc[g] += (cv[g] * e_lds[g][h][t4]) * w4;
    }
  }
  if (half == 1) {
#pragma unroll
    for (int g = 0; g < 4; ++g) *(f32x4*)&red[t8][g][0] = acc[g];
  }
  __syncthreads();
  if (half == 0) {
    const float al = alpha[0];
#pragma unroll
    for (int g = 0; g < 4; ++g) {
      acc[g] = (acc[g] + *(const f32x4*)&red[t8][g][0]) * al;
      *(f32x4*)(v_buf + (size_t)(g0 + g) * 1024 + c * 8 + dh) = acc[g];
      float ss = acc[g][0]*acc[g][0] + acc[g][1]*acc[g][1] + acc[g][2]*acc[g][2] + acc[g][3]*acc[g][3];
      ss += __shfl_xor(ss, 1);
      if ((tid & 1) == 0) vn_buf[(g0 + g) * 128 + c] = sqrtf(ss) * w_scale[c] + bias_vec[c];
    }
  }
}

// ---------------- logits = vn @ E^T (MFMA bf16), into d_out ----------------
__global__ __launch_bounds__(512) void logits_kernel(
    const float* __restrict__ vn, const short* __restrict__ Ebf,
    float* __restrict__ out)
{
  __shared__ short et[64][136];
  const int n0 = blockIdx.x * 64;
  const int m0 = blockIdx.y * 128;
  const int tid = threadIdx.x;
  const int wave = tid >> 6, lane = tid & 63, lrow = lane & 15, lk8 = lane >> 4;
  {
    const int r = tid >> 3, ks = (tid & 7) * 16;
    const int v = n0 + r;
    bf16x8 a = {0,0,0,0,0,0,0,0}, b = {0,0,0,0,0,0,0,0};
    if (v < 50001) {
      a = *(const bf16x8*)(Ebf + (size_t)v * 128 + ks);
      b = *(const bf16x8*)(Ebf + (size_t)v * 128 + ks + 8);
    }
    *(bf16x8*)&et[r][ks] = a;
    *(bf16x8*)&et[r][ks + 8] = b;
  }
  __syncthreads();
  const int arow = m0 + wave * 16 + lrow;
  bf16x8 afr[4];
#pragma unroll
  for (int kt = 0; kt < 4; ++kt) {
    const float* p = vn + (size_t)arow * 128 + kt * 32 + lk8 * 8;
    afr[kt] = pack8v(*(const f32x4*)p, *(const f32x4*)(p + 4));
  }
  f32x4 acc[4] = {{0,0,0,0},{0,0,0,0},{0,0,0,0},{0,0,0,0}};
#pragma unroll
  for (int kt = 0; kt < 4; ++kt) {
#pragma unroll
    for (int nt = 0; nt < 4; ++nt) {
      const bf16x8 bfr = *(const bf16x8*)&et[nt * 16 + lrow][kt * 32 + lk8 * 8];
      acc[nt] = mfma16(afr[kt], bfr, acc[nt]);
    }
  }
#pragma unroll
  for (int nt = 0; nt < 4; ++nt) {
    const int col = n0 + nt * 16 + lrow;
    if (col < 50001) {
      const int row = m0 + wave * 16 + lk8 * 4;
#pragma unroll
      for (int e2 = 0; e2 < 4; ++e2)
        out[(size_t)(row + e2) * 50001 + col] = acc[nt][e2];
    }
  }
}

// ---------------- per-row softmax stats over 50001 logits ----------------
__global__ __launch_bounds__(256) void rowstats_kernel(
    const float* __restrict__ out, float* __restrict__ row_m, float* __restrict__ row_inv)
{
  const int b = blockIdx.x;
  const int tid = threadIdx.x;
  const float* row = out + (size_t)b * 50001;
  float m = -1e30f, s = 0.f;
  for (int i = tid; i < 50001; i += 256) {
    const float x = row[i];
    const float nm = fmaxf(m, x);
    s = s * __expf(m - nm) + __expf(x - nm);
    m = nm;
  }
#pragma unroll
  for (int off = 32; off > 0; off >>= 1) {
    const float m2 = __shfl_xor(m, off), s2 = __shfl_xor(s, off);
    const float nm = fmaxf(m, m2);
    s = s * __expf(m - nm) + s2 * __expf(m2 - nm);
    m = nm;
  }
  __shared__ float ms[4], ss[4];
  const int wv = tid >> 6, ln = tid & 63;
  if (ln == 0) { ms[wv] = m; ss[wv] = s; }
  __syncthreads();
  if (tid == 0) {
    float M = ms[0], S = ss[0];
    for (int w = 1; w < 4; ++w) {
      const float nm = fmaxf(M, ms[w]);
      S = S * __expf(M - nm) + ss[w] * __expf(ms[w] - nm);
      M = nm;
    }
    row_m[b] = M;
    row_inv[b] = 1.f / S;
  }
}

// ---------------- p = softmax(logits) @ E  (split-K MFMA, atomic accumulate) ----------------
__global__ __launch_bounds__(256) void pgemm_kernel(
    const float* __restrict__ out, const short* __restrict__ Et,
    const float* __restrict__ row_m, const float* __restrict__ row_inv,
    float* __restrict__ p_buf)
{
  const int tid = threadIdx.x;
  const int wave = tid >> 6, lane = tid & 63, lrow = lane & 15, lk8 = lane >> 4;
  const int m0 = blockIdx.y * 64;
  const int row = m0 + wave * 16 + lrow;
  const float rm = row_m[row], ri = row_inv[row];
  const float* lp = out + (size_t)row * 50001;
  const int kbeg = blockIdx.x * 1024;
  f32x4 acc[8] = {{0,0,0,0},{0,0,0,0},{0,0,0,0},{0,0,0,0},
                  {0,0,0,0},{0,0,0,0},{0,0,0,0},{0,0,0,0}};
  if (kbeg + 1024 <= 50001) {
    for (int v0 = kbeg; v0 < kbeg + 1024; v0 += 32) {
      const int kb = v0 + lk8 * 8;
      float x[8];
      __builtin_memcpy(x, lp + kb, 32);
      bf16x8 afr;
#pragma unroll
      for (int j = 0; j < 8; ++j) afr[j] = f2bf(__expf(x[j] - rm) * ri);
#pragma unroll
      for (int nt = 0; nt < 8; ++nt) {
        const bf16x8 bfr = *(const bf16x8*)(Et + (size_t)(nt * 16 + lrow) * 50048 + kb);
        acc[nt] = mfma16(afr, bfr, acc[nt]);
      }
    }
  } else {
    const int kend = 50001;
    for (int v0 = kbeg; v0 < kend; v0 += 32) {
      const int kb = v0 + lk8 * 8;
      float x[8];
#pragma unroll
      for (int j = 0; j < 8; ++j) x[j] = (kb + j < 50001) ? lp[kb + j] : rm - 100.f;
      bf16x8 afr;
#pragma unroll
      for (int j = 0; j < 8; ++j) afr[j] = f2bf(__expf(x[j] - rm) * ri);
#pragma unroll
      for (int nt = 0; nt < 8; ++nt) {
        const bf16x8 bfr = *(const bf16x8*)(Et + (size_t)(nt * 16 + lrow) * 50048 + kb);
        acc[nt] = mfma16(afr, bfr, acc[nt]);
      }
    }
  }
#pragma unroll
  for (int nt = 0; nt < 8; ++nt)
#pragma unroll
    for (int e2 = 0; e2 < 4; ++e2)
      atomicAdd(&p_buf[(size_t)(m0 + wave * 16 + lk8 * 4 + e2) * 128 + nt * 16 + lrow], acc[nt][e2]);
}

// ---------------- coef = concat(p, v) @ W_coef ----------------
__global__ __launch_bounds__(256) void coef_kernel(
    const float* __restrict__ p_buf, const float* __restrict__ v_buf,
    const float* __restrict__ W_coef, float* __restrict__ coef_buf)
{
  __shared__ float p_lds[4][128];
  const int g0 = blockIdx.x * 4;
  const int tid = threadIdx.x;
  for (int i = tid; i < 512; i += 256) ((float*)p_lds)[i] = p_buf[(size_t)g0 * 128 + i];
  __syncthreads();
  const int c = tid >> 1, dh = (tid & 1) * 4;
  float vg[4][8];
#pragma unroll
  for (int g = 0; g < 4; ++g) {
    const f32x4 va = *(const f32x4*)(v_buf + (size_t)(g0 + g) * 1024 + c * 8);
    const f32x4 vb = *(const f32x4*)(v_buf + (size_t)(g0 + g) * 1024 + c * 8 + 4);
    vg[g][0]=va[0]; vg[g][1]=va[1]; vg[g][2]=va[2]; vg[g][3]=va[3];
    vg[g][4]=vb[0]; vg[g][5]=vb[1]; vg[g][6]=vb[2]; vg[g][7]=vb[3];
  }
  const float* wc = W_coef + (size_t)c * 1088 + dh;
  f32x4 acc[4] = {{0,0,0,0},{0,0,0,0},{0,0,0,0},{0,0,0,0}};
  for (int dp = 0; dp < 128; ++dp) {
    const f32x4 w4 = *(const f32x4*)(wc + (size_t)dp * 8);
#pragma unroll
    for (int g = 0; g < 4; ++g) acc[g] += p_lds[g][dp] * w4;
  }
#pragma unroll
  for (int q = 0; q < 8; ++q) {
    const f32x4 w4 = *(const f32x4*)(wc + (size_t)(128 + q) * 8);
#pragma unroll
    for (int g = 0; g < 4; ++g) acc[g] += vg[g][q] * w4;
  }
#pragma unroll
  for (int g = 0; g < 4; ++g)
    *(f32x4*)(coef_buf + (size_t)(g0 + g) * 1024 + c * 8 + dh) = acc[g];
}

// ---------------- b (+)= sum_t e * (sum_d W * coef)  (512 thr, h-partitioned) ----------------
template<bool FIRST>
__global__ __launch_bounds__(512) void bupd_kernel(
    const float* __restrict__ coef_buf, const float* __restrict__ e_buf,
    const float* __restrict__ W, float* __restrict__ b_state)
{
  __shared__ float e_lds[4][128][4];
  const int g0 = blockIdx.x * 4;
  const int tid = threadIdx.x;
  for (int i = tid; i < 2048; i += 512) ((float*)e_lds)[i] = e_buf[(size_t)g0 * 512 + i];
  __syncthreads();
  const int half = tid >> 8;
  const int t8 = tid & 255;
  const int c = t8 >> 1, dh = (t8 & 1) * 4;
  f32x4 cf[4];
#pragma unroll
  for (int g = 0; g < 4; ++g)
    cf[g] = *(const f32x4*)(coef_buf + (size_t)(g0 + g) * 1024 + c * 8 + dh);
  const int hbeg = half * 64, hend = hbeg + 64;
  for (int h = hbeg; h < hend; ++h) {
    float accg[4] = {0.f, 0.f, 0.f, 0.f};
#pragma unroll
    for (int t4 = 0; t4 < 4; ++t4) {
      const f32x4 w4 = *(const f32x4*)(W + ((size_t)(h * 4 + t4) * 128 + c) * 8 + dh);
#pragma unroll
      for (int g = 0; g < 4; ++g) {
        const float d4 = w4[0]*cf[g][0] + w4[1]*cf[g][1] + w4[2]*cf[g][2] + w4[3]*cf[g][3];
        accg[g] += e_lds[g][h][t4] * d4;
      }
    }
#pragma unroll
    for (int g = 0; g < 4; ++g) {
      const float full = accg[g] + __shfl_xor(accg[g], 1);
      if ((tid & 1) == 0) {
        float* dst = &b_state[(size_t)(g0 + g) * 16384 + h * 128 + c];
        if (FIRST) *dst = full; else *dst += full;
      }
    }
  }
}

extern "C" void kernel_launch(void* const* d_in, const int* in_sizes, int n_in,
                              void* d_out, int out_size, void* d_ws, size_t ws_size,
                              hipStream_t stream) {
  const int* seq0 = (const int*)d_in[0];
  const int* seq1 = (const int*)d_in[1];
  const int* seq2 = (const int*)d_in[2];
  const int* seq3 = (const int*)d_in[3];
  const float* item_emb = (const float*)d_in[4];
  const float* Wih = (const float*)d_in[5];
  const float* Whh = (const float*)d_in[6];
  const float* bih = (const float*)d_in[7];
  const float* bhh = (const float*)d_in[8];
  const float* W = (const float*)d_in[9];
  const float* w_scale = (const float*)d_in[10];
  const float* bias_vec = (const float*)d_in[11];
  const float* alpha = (const float*)d_in[12];
  const float* W_coef = (const float*)d_in[13];
  float* out = (float*)d_out;

  char* ws = (char*)d_ws;
  float* e_buf    = (float*)(ws);                 // 1,048,576 B
  float* b_state  = (float*)(ws + 1048576);       // 33,554,432 B
  float* v_buf    = (float*)(ws + 34603008);      // 2,097,152 B
  float* vn_buf   = (float*)(ws + 36700160);      // 262,144 B
  float* p_buf    = (float*)(ws + 36962304);      // 262,144 B
  float* coef_buf = (float*)(ws + 37224448);      // 2,097,152 B
  float* row_m    = (float*)(ws + 39321600);      // 2,048 B
  float* row_inv  = (float*)(ws + 39323648);      // 2,048 B
  short* Ebf      = (short*)(ws + 39325696);      // 12,800,256 B
  short* Et       = (short*)(ws + 52125952);      // 12,812,288 B  (total ~64.9 MB)

  // gi scratch: t50 behaviors (59.0 MB) overlaps [b_state..Et) -- lifetime ends
  // before cast_ebf/build_et below; b_state is first written by bupd<FIRST>.
  // click gi (78.6 MB) lives in d_out until the first logits write.
  unsigned short* gi_t50   = (unsigned short*)(ws + 1048576);
  unsigned short* gi_click = (unsigned short*)d_out;

  gi_gemm_kernel<<<dim3(700), 512, 0, stream>>>(seq0, seq1, seq2, seq3, item_emb, Wih,
                                                gi_t50, gi_click);
  gru_rec3_kernel<<<dim3(256), 256, 0, stream>>>(Whh, bih, bhh, gi_t50, gi_click, e_buf);
  cast_ebf<<<dim3(25001), 256, 0, stream>>>(item_emb, Ebf);
  build_et<<<dim3(782), 256, 0, stream>>>(item_emb, Et);

  // iter 0 (b = 0 implicitly)
  caps_v_kernel<true><<<dim3(128), 512, 0, stream>>>(b_state, e_buf, W, w_scale, bias_vec,
                                                     alpha, v_buf, vn_buf);
  logits_kernel<<<dim3(782, 4), 512, 0, stream>>>(vn_buf, Ebf, out);
  rowstats_kernel<<<dim3(512), 256, 0, stream>>>(out, row_m, row_inv);
  hipMemsetAsync(p_buf, 0, 262144, stream);
  pgemm_kernel<<<dim3(49, 8), 256, 0, stream>>>(out, Et, row_m, row_inv, p_buf);
  coef_kernel<<<dim3(128), 256, 0, stream>>>(p_buf, v_buf, W_coef, coef_buf);
  bupd_kernel<true><<<dim3(128), 512, 0, stream>>>(coef_buf, e_buf, W, b_state);
  // iter 1
  caps_v_kernel<false><<<dim3(128), 512, 0, stream>>>(b_state, e_buf, W, w_scale, bias_vec,
                                                      alpha, v_buf, vn_buf);
  logits_kernel<<<dim3(782, 4), 512, 0, stream>>>(vn_buf, Ebf, out);
  rowstats_kernel<<<dim3(512), 256, 0, stream>>>(out, row_m, row_inv);
  hipMemsetAsync(p_buf, 0, 262144, stream);
  pgemm_kernel<<<dim3(49, 8), 256, 0, stream>>>(out, Et, row_m, row_inv, p_buf);
  coef_kernel<<<dim3(128), 256, 0, stream>>>(p_buf, v_buf, W_coef, coef_buf);
  bupd_kernel<false><<<dim3(128), 512, 0, stream>>>(coef_buf, e_buf, W, b_state);
  // final
  caps_v_kernel<false><<<dim3(128), 512, 0, stream>>>(b_state, e_buf, W, w_scale, bias_vec,
                                                      alpha, v_buf, vn_buf);
  logits_kernel<<<dim3(782, 4), 512, 0, stream>>>(vn_buf, Ebf, out);
}

// Round 7
// 1020.476 us; speedup vs baseline: 1.3524x; 1.1211x over previous
//
#include <hip/hip_runtime.h>
#include <math.h>

typedef __attribute__((ext_vector_type(8))) short bf16x8;
typedef __attribute__((ext_vector_type(4))) float f32x4;
typedef __attribute__((ext_vector_type(4))) unsigned short u16x4;
typedef __attribute__((ext_vector_type(4))) _Float16 f16x4;
typedef __attribute__((ext_vector_type(8))) _Float16 f16x8;

static __device__ __forceinline__ short f2bf(float f) {
  unsigned u = __builtin_bit_cast(unsigned, f);
  u += 0x7fffu + ((u >> 16) & 1u);
  return (short)(u >> 16);
}
static __device__ __forceinline__ float bf2f(unsigned short s) {
  unsigned u = ((unsigned)s) << 16;
  return __builtin_bit_cast(float, u);
}
static __device__ __forceinline__ f32x4 mfma16(bf16x8 a, bf16x8 b, f32x4 c) {
  return __builtin_amdgcn_mfma_f32_16x16x32_bf16(a, b, c, 0, 0, 0);
}
static __device__ __forceinline__ bf16x8 pack8v(f32x4 a, f32x4 b) {
  bf16x8 r;
  r[0]=f2bf(a[0]); r[1]=f2bf(a[1]); r[2]=f2bf(a[2]); r[3]=f2bf(a[3]);
  r[4]=f2bf(b[0]); r[5]=f2bf(b[1]); r[6]=f2bf(b[2]); r[7]=f2bf(b[3]);
  return r;
}
static __device__ __forceinline__ float fastrcp(float x) {
  float r;
  asm("v_rcp_f32_e32 %0, %1" : "=v"(r) : "v"(x));
  return r;
}

// LDS-only barrier: does NOT drain vmcnt, global prefetch stays in flight.
#define LGKM_BARRIER() do {                                   \
    asm volatile("s_waitcnt lgkmcnt(0)" ::: "memory");        \
    __builtin_amdgcn_s_barrier();                             \
    __builtin_amdgcn_sched_barrier(0);                        \
  } while (0)

// ---------------- cast item_emb -> bf16 (row-major) ----------------
__global__ __launch_bounds__(256) void cast_ebf(const float* __restrict__ E, short* __restrict__ Ebf) {
  int i = blockIdx.x * 256 + threadIdx.x;
  if (i < 50001 * 128) Ebf[i] = f2bf(E[i]);
}

// ---------------- build E^T bf16 [128][50048] (zero-padded) ----------------
__global__ __launch_bounds__(256) void build_et(const float* __restrict__ E, short* __restrict__ Et) {
  __shared__ float tile[64][132];
  const int v0 = blockIdx.x * 64;
  const int tid = threadIdx.x;
  const int r = tid >> 2, ks = (tid & 3) * 32;
  const int v = v0 + r;
  for (int j = 0; j < 32; j += 4) {
    f32x4 x = {0.f, 0.f, 0.f, 0.f};
    if (v < 50001) x = *(const f32x4*)(E + (size_t)v * 128 + ks + j);
    *(f32x4*)&tile[r][ks + j] = x;
  }
  __syncthreads();
  const int k = tid >> 1, vs = (tid & 1) * 32;
  for (int j = 0; j < 32; ++j)
    Et[(size_t)k * 50048 + v0 + vs + j] = f2bf(tile[vs + j][k]);
}

// ---------------- gi = x @ Wih^T for all (row,t), stored as compact 4-row quad tiles ----------------
// quad tile (4 batch rows at one t): [gate(3)][col(128)][row(4)] ushort = 1536 ushorts (3 KB)
// quad q = batch_row>>2; click: base = gi_click + (q*200 + t)*1536; t50: gi_t50 + beh*9830400 + (q*50+t)*1536
__global__ __launch_bounds__(512) void gi_gemm_kernel(
    const int* __restrict__ seq0, const int* __restrict__ seq1,
    const int* __restrict__ seq2, const int* __restrict__ seq3,
    const float* __restrict__ item_emb, const float* __restrict__ Wih,
    unsigned short* __restrict__ gi_t50, unsigned short* __restrict__ gi_click)
{
  const int b = blockIdx.x;           // 700 blocks, 16 tiles (16-row) each
  int beh, tile0;
  if (b < 100)      { beh = 0; tile0 = b * 16; }
  else if (b < 200) { beh = 1; tile0 = (b - 100) * 16; }
  else if (b < 300) { beh = 2; tile0 = (b - 200) * 16; }
  else              { beh = 3; tile0 = (b - 300) * 16; }
  const int T = (beh == 3) ? 200 : 50;
  const int* seq = (beh == 0) ? seq0 : (beh == 1) ? seq1 : (beh == 2) ? seq2 : seq3;
  unsigned short* gibase = (beh == 3) ? gi_click : (gi_t50 + (size_t)beh * 9830400);

  const int tid = threadIdx.x;
  const int wave = tid >> 6, lane = tid & 63, lrow = lane & 15, lk8 = lane >> 4;
  const int bcol = wave * 16 + lrow;

  bf16x8 wif[3][4];
  const float* WihB = Wih + (size_t)beh * 384 * 128;
#pragma unroll
  for (int g = 0; g < 3; ++g) {
    const int wr = g * 128 + bcol;
#pragma unroll
    for (int kt = 0; kt < 4; ++kt) {
      const int k0 = kt * 32 + lk8 * 8;
      f32x4 a0 = *(const f32x4*)(WihB + (size_t)wr * 128 + k0);
      f32x4 a1 = *(const f32x4*)(WihB + (size_t)wr * 128 + k0 + 4);
      wif[g][kt] = pack8v(a0, a1);
    }
  }

  __shared__ short xt[16][132];
  const int gj = tid >> 5;
  const int gc = (tid & 31) * 4;

  for (int ti = 0; ti < 16; ++ti) {
    const int tile = tile0 + ti;
    const int r0blk = tile / T;         // 16-row group 0..31
    const int t = tile - r0blk * T;
    {
      const int sidx = seq[(size_t)(r0blk * 16 + gj) * T + t];
      const f32x4 xv = *(const f32x4*)(item_emb + (size_t)sidx * 128 + gc);
      xt[gj][gc]     = f2bf(xv[0]);
      xt[gj][gc + 1] = f2bf(xv[1]);
      xt[gj][gc + 2] = f2bf(xv[2]);
      xt[gj][gc + 3] = f2bf(xv[3]);
    }
    __syncthreads();
    bf16x8 ax[4];
#pragma unroll
    for (int kt = 0; kt < 4; ++kt)
      ax[kt] = *(const bf16x8*)&xt[lrow][kt * 32 + lk8 * 8];
    f32x4 acc[3] = {{0,0,0,0},{0,0,0,0},{0,0,0,0}};
#pragma unroll
    for (int kt = 0; kt < 4; ++kt) {
      acc[0] = mfma16(ax[kt], wif[0][kt], acc[0]);
      acc[1] = mfma16(ax[kt], wif[1][kt], acc[1]);
      acc[2] = mfma16(ax[kt], wif[2][kt], acc[2]);
    }
    // C row m = lk8*4+e2 -> batch row r0blk*16+m; quad = r0blk*4 + lk8, row-in-quad = e2
    unsigned short* base = gibase + ((size_t)(r0blk * 4 + lk8) * T + t) * 1536;
    unsigned short* dst = base + bcol * 4;
#pragma unroll
    for (int g = 0; g < 3; ++g) {
      u16x4 o;
      o[0] = (unsigned short)f2bf(acc[g][0]);
      o[1] = (unsigned short)f2bf(acc[g][1]);
      o[2] = (unsigned short)f2bf(acc[g][2]);
      o[3] = (unsigned short)f2bf(acc[g][3]);
      *(u16x4*)(dst + g * 512) = o;
    }
    __syncthreads();
  }
}

// ---------------- GRU recurrence: 4 rows/block, 512 blocks (2/CU), epilogue 1 e2/lane ----------------
// batch row r (0..3) lives in MFMA M-slot r*4 -> lane lk8=r, e2=0 holds it
__global__ __launch_bounds__(256, 2) void gru_rec5_kernel(
    const float* __restrict__ Whh, const float* __restrict__ bih,
    const float* __restrict__ bhh,
    const unsigned short* __restrict__ gi_t50,
    const unsigned short* __restrict__ gi_click,
    float* __restrict__ e_out)
{
  const int beh = blockIdx.x >> 7;      // 4 beh x 128 quads
  const int qt = blockIdx.x & 127;
  const int T = (beh == 3) ? 200 : 50;
  const unsigned short* gib =
      ((beh == 3) ? gi_click : (gi_t50 + (size_t)beh * 9830400)) + (size_t)qt * T * 1536;

  const int tid = threadIdx.x;
  const int w = tid >> 6;
  const int lane = tid & 63;
  const int lrow = lane & 15;
  const int lk8 = lane >> 4;
  const int col0 = w * 32 + lrow;       // ct=0
  const int col1 = col0 + 16;           // ct=1

  __shared__ short h0[16][140];
  __shared__ short h1[16][140];

  // Whh B-fragments: 3 gates x 2 col-tiles x 4 ktiles = 96 VGPR
  bf16x8 whf[3][2][4];
  const float* WhhB = Whh + (size_t)beh * 384 * 128;
#pragma unroll
  for (int g = 0; g < 3; ++g) {
#pragma unroll
    for (int ct = 0; ct < 2; ++ct) {
      const int wr = g * 128 + (ct ? col1 : col0);
#pragma unroll
      for (int kt = 0; kt < 4; ++kt) {
        const int k0 = kt * 32 + lk8 * 8;
        f32x4 b0 = *(const f32x4*)(WhhB + (size_t)wr * 128 + k0);
        f32x4 b1 = *(const f32x4*)(WhhB + (size_t)wr * 128 + k0 + 4);
        whf[g][ct][kt] = pack8v(b0, b1);
      }
    }
  }
  float bR[2], bZ[2], bN[2], bHN[2];
#pragma unroll
  for (int ct = 0; ct < 2; ++ct) {
    const int c = ct ? col1 : col0;
    bR[ct]  = bih[beh * 384 + c] + bhh[beh * 384 + c];
    bZ[ct]  = bih[beh * 384 + 128 + c] + bhh[beh * 384 + 128 + c];
    bN[ct]  = bih[beh * 384 + 256 + c];
    bHN[ct] = bhh[beh * 384 + 256 + c];
  }

  for (int i = tid; i < 16 * 140; i += 256) { ((short*)h0)[i] = 0; ((short*)h1)[i] = 0; }
  float hreg[2] = {0.f, 0.f};
  __syncthreads();

  // gi element for (t, ct, g): gib[t*1536 + g*512 + col_ct*4 + lk8]
  const unsigned short* gp0 = gib + col0 * 4 + lk8;
  const unsigned short* gp1 = gib + col1 * 4 + lk8;

  unsigned short ga[30], gb[30];   // 5 steps x 2ct x 3g

#define LOAD_CHUNK(BUF, C0) do {                                              \
    _Pragma("unroll")                                                         \
    for (int _s = 0; _s < 5; ++_s) {                                          \
      const size_t _o = (size_t)((C0) + _s) * 1536;                           \
      _Pragma("unroll")                                                       \
      for (int _g = 0; _g < 3; ++_g) {                                        \
        BUF[_s * 6 + 0 * 3 + _g] = gp0[_o + _g * 512];                        \
        BUF[_s * 6 + 1 * 3 + _g] = gp1[_o + _g * 512];                        \
      }                                                                       \
    }                                                                         \
  } while (0)

  short (*hin)[140] = h0;
  short (*hout)[140] = h1;

#define STEP(BUF, S) do {                                                     \
    bf16x8 ah[4];                                                             \
    _Pragma("unroll")                                                         \
    for (int kt = 0; kt < 4; ++kt)                                            \
      ah[kt] = *(const bf16x8*)&hin[lrow][kt * 32 + lk8 * 8];                 \
    f32x4 hr_[2], hz_[2], hn_[2];                                             \
    _Pragma("unroll")                                                         \
    for (int ct = 0; ct < 2; ++ct) {                                          \
      hr_[ct] = (f32x4){0,0,0,0}; hz_[ct] = (f32x4){0,0,0,0}; hn_[ct] = (f32x4){0,0,0,0}; \
      _Pragma("unroll")                                                       \
      for (int kt = 0; kt < 4; ++kt) {                                        \
        hr_[ct] = mfma16(ah[kt], whf[0][ct][kt], hr_[ct]);                    \
        hz_[ct] = mfma16(ah[kt], whf[1][ct][kt], hz_[ct]);                    \
        hn_[ct] = mfma16(ah[kt], whf[2][ct][kt], hn_[ct]);                    \
      }                                                                       \
    }                                                                         \
    _Pragma("unroll")                                                         \
    for (int ct = 0; ct < 2; ++ct) {                                          \
      const float xr = bf2f(BUF[(S)*6 + ct*3 + 0]) + bR[ct] + hr_[ct][0];     \
      const float xz = bf2f(BUF[(S)*6 + ct*3 + 1]) + bZ[ct] + hz_[ct][0];     \
      const float ea = __expf(-xr);                                           \
      const float eb = __expf(-xz);                                           \
      const float pa = 1.f + ea, pb = 1.f + eb;                               \
      const float rd = fastrcp(pa * pb);                                      \
      const float rr = pb * rd;                                               \
      const float zz = pa * rd;                                               \
      const float tn = bf2f(BUF[(S)*6 + ct*3 + 2]) + bN[ct] + rr * (hn_[ct][0] + bHN[ct]); \
      const float tt = __expf(-2.f * tn);                                     \
      const float nn = (1.f - tt) * fastrcp(1.f + tt);                        \
      hreg[ct] = nn + zz * (hreg[ct] - nn);                                   \
      hout[lk8 * 4][ct ? col1 : col0] = f2bf(hreg[ct]);                       \
    }                                                                         \
    LGKM_BARRIER();                                                           \
    short (*_tmp)[140] = hin; hin = hout; hout = _tmp;                        \
  } while (0)

  LOAD_CHUNK(ga, 0);
  for (int c = 0; c < T; c += 10) {
    if (c + 5 < T) LOAD_CHUNK(gb, c + 5);
    STEP(ga, 0); STEP(ga, 1); STEP(ga, 2); STEP(ga, 3); STEP(ga, 4);
    if (c + 10 < T) LOAD_CHUNK(ga, c + 10);
    STEP(gb, 0); STEP(gb, 1); STEP(gb, 2); STEP(gb, 3); STEP(gb, 4);
  }
#undef STEP
#undef LOAD_CHUNK

#pragma unroll
  for (int ct = 0; ct < 2; ++ct)
    e_out[(size_t)(qt * 4 + lk8) * 512 + (ct ? col1 : col0) * 4 + beh] = hreg[ct];
}

// ---------------- caps: c = softmax(b), v = alpha * sum_h c*u, v_ = ||v||*ws+bias ----------------
template<bool FIRST>
__global__ __launch_bounds__(512) void caps_v_kernel(
    const float* __restrict__ b_state, const float* __restrict__ e_buf,
    const float* __restrict__ W, const float* __restrict__ w_scale,
    const float* __restrict__ bias_vec, const float* __restrict__ alpha,
    float* __restrict__ v_buf, float* __restrict__ vn_buf)
{
  __shared__ float e_lds[4][128][4];
  __shared__ float stat_m[4][128];
  __shared__ float stat_i[4][128];
  __shared__ float red[256][4][4];
  const int g0 = blockIdx.x * 4;
  const int tid = threadIdx.x;
  for (int i = tid; i < 2048; i += 512) ((float*)e_lds)[i] = e_buf[(size_t)g0 * 512 + i];
  if (!FIRST) {
    const int wv = tid >> 6, ln = tid & 63;
    for (int ri = wv; ri < 512; ri += 8) {
      const int g = ri >> 7, h = ri & 127;
      const float* row = b_state + (size_t)(g0 + g) * 16384 + h * 128;
      const float x0 = row[ln], x1 = row[ln + 64];
      float m = fmaxf(x0, x1);
#pragma unroll
      for (int off = 32; off > 0; off >>= 1) m = fmaxf(m, __shfl_xor(m, off));
      float s = __expf(x0 - m) + __expf(x1 - m);
#pragma unroll
      for (int off = 32; off > 0; off >>= 1) s += __shfl_xor(s, off);
      if (ln == 0) { stat_m[g][h] = m; stat_i[g][h] = 1.f / s; }
    }
  }
  __syncthreads();
  const int half = tid >> 8;
  const int t8 = tid & 255;
  const int c = t8 >> 1, dh = (t8 & 1) * 4;
  f32x4 acc[4] = {{0,0,0,0},{0,0,0,0},{0,0,0,0},{0,0,0,0}};
  const int hbeg = half * 64, hend = hbeg + 64;
  for (int h = hbeg; h < hend; ++h) {
    float cv[4];
#pragma unroll
    for (int g = 0; g < 4; ++g)
      cv[g] = FIRST ? 0.0078125f
            : __expf(b_state[(size_t)(g0 + g) * 16384 + h * 128 + c] - stat_m[g][h]) * stat_i[g][h];
#pragma unroll
    for (int t4 = 0; t4 < 4; ++t4) {
      const f32x4 w4 = *(const f32x4*)(W + ((size_t)(h * 4 + t4) * 128 + c) * 8 + dh);
#pragma unroll
      for (int g = 0; g < 4; ++g) acc[g] += (cv[g] * e_lds[g][h][t4]) * w4;
    }
  }
  if (half == 1) {
#pragma unroll
    for (int g = 0; g < 4; ++g) *(f32x4*)&red[t8][g][0] = acc[g];
  }
  __syncthreads();
  if (half == 0) {
    const float al = alpha[0];
#pragma unroll
    for (int g = 0; g < 4; ++g) {
      acc[g] = (acc[g] + *(const f32x4*)&red[t8][g][0]) * al;
      *(f32x4*)(v_buf + (size_t)(g0 + g) * 1024 + c * 8 + dh) = acc[g];
      float ss = acc[g][0]*acc[g][0] + acc[g][1]*acc[g][1] + acc[g][2]*acc[g][2] + acc[g][3]*acc[g][3];
      ss += __shfl_xor(ss, 1);
      if ((tid & 1) == 0) vn_buf[(g0 + g) * 128 + c] = sqrtf(ss) * w_scale[c] + bias_vec[c];
    }
  }
}

// ---------------- iter logits (fp16, stride 50048, pad = -6e4), into d_out ----------------
__global__ __launch_bounds__(512) void logits16_kernel(
    const float* __restrict__ vn, const short* __restrict__ Ebf,
    _Float16* __restrict__ out16)
{
  __shared__ short et[64][136];
  const int n0 = blockIdx.x * 64;
  const int m0 = blockIdx.y * 128;
  const int tid = threadIdx.x;
  const int wave = tid >> 6, lane = tid & 63, lrow = lane & 15, lk8 = lane >> 4;
  {
    const int r = tid >> 3, ks = (tid & 7) * 16;
    const int v = n0 + r;
    bf16x8 a = {0,0,0,0,0,0,0,0}, b = {0,0,0,0,0,0,0,0};
    if (v < 50001) {
      a = *(const bf16x8*)(Ebf + (size_t)v * 128 + ks);
      b = *(const bf16x8*)(Ebf + (size_t)v * 128 + ks + 8);
    }
    *(bf16x8*)&et[r][ks] = a;
    *(bf16x8*)&et[r][ks + 8] = b;
  }
  __syncthreads();
  const int arow = m0 + wave * 16 + lrow;
  bf16x8 afr[4];
#pragma unroll
  for (int kt = 0; kt < 4; ++kt) {
    const float* p = vn + (size_t)arow * 128 + kt * 32 + lk8 * 8;
    afr[kt] = pack8v(*(const f32x4*)p, *(const f32x4*)(p + 4));
  }
  f32x4 acc[4] = {{0,0,0,0},{0,0,0,0},{0,0,0,0},{0,0,0,0}};
#pragma unroll
  for (int kt = 0; kt < 4; ++kt) {
#pragma unroll
    for (int nt = 0; nt < 4; ++nt) {
      const bf16x8 bfr = *(const bf16x8*)&et[nt * 16 + lrow][kt * 32 + lk8 * 8];
      acc[nt] = mfma16(afr[kt], bfr, acc[nt]);
    }
  }
#pragma unroll
  for (int nt = 0; nt < 4; ++nt) {
    const int col = n0 + nt * 16 + lrow;
    const int row = m0 + wave * 16 + lk8 * 4;
#pragma unroll
    for (int e2 = 0; e2 < 4; ++e2) {
      const float v = (col < 50001) ? acc[nt][e2] : -60000.f;
      out16[(size_t)(row + e2) * 50048 + col] = (_Float16)v;
    }
  }
}

// ---------------- final logits (fp32) into d_out ----------------
__global__ __launch_bounds__(512) void logits_kernel(
    const float* __restrict__ vn, const short* __restrict__ Ebf,
    float* __restrict__ out)
{
  __shared__ short et[64][136];
  const int n0 = blockIdx.x * 64;
  const int m0 = blockIdx.y * 128;
  const int tid = threadIdx.x;
  const int wave = tid >> 6, lane = tid & 63, lrow = lane & 15, lk8 = lane >> 4;
  {
    const int r = tid >> 3, ks = (tid & 7) * 16;
    const int v = n0 + r;
    bf16x8 a = {0,0,0,0,0,0,0,0}, b = {0,0,0,0,0,0,0,0};
    if (v < 50001) {
      a = *(const bf16x8*)(Ebf + (size_t)v * 128 + ks);
      b = *(const bf16x8*)(Ebf + (size_t)v * 128 + ks + 8);
    }
    *(bf16x8*)&et[r][ks] = a;
    *(bf16x8*)&et[r][ks + 8] = b;
  }
  __syncthreads();
  const int arow = m0 + wave * 16 + lrow;
  bf16x8 afr[4];
#pragma unroll
  for (int kt = 0; kt < 4; ++kt) {
    const float* p = vn + (size_t)arow * 128 + kt * 32 + lk8 * 8;
    afr[kt] = pack8v(*(const f32x4*)p, *(const f32x4*)(p + 4));
  }
  f32x4 acc[4] = {{0,0,0,0},{0,0,0,0},{0,0,0,0},{0,0,0,0}};
#pragma unroll
  for (int kt = 0; kt < 4; ++kt) {
#pragma unroll
    for (int nt = 0; nt < 4; ++nt) {
      const bf16x8 bfr = *(const bf16x8*)&et[nt * 16 + lrow][kt * 32 + lk8 * 8];
      acc[nt] = mfma16(afr[kt], bfr, acc[nt]);
    }
  }
#pragma unroll
  for (int nt = 0; nt < 4; ++nt) {
    const int col = n0 + nt * 16 + lrow;
    if (col < 50001) {
      const int row = m0 + wave * 16 + lk8 * 4;
#pragma unroll
      for (int e2 = 0; e2 < 4; ++e2)
        out[(size_t)(row + e2) * 50001 + col] = acc[nt][e2];
    }
  }
}

// ---------------- per-row softmax stats (fp16 logits), 2-pass ----------------
__global__ __launch_bounds__(256) void rowstats16_kernel(
    const _Float16* __restrict__ lg, float* __restrict__ row_m, float* __restrict__ row_inv)
{
  const int b = blockIdx.x;
  const int tid = threadIdx.x;
  const _Float16* row = lg + (size_t)b * 50048;
  __shared__ float ms[4], ss[4];
  __shared__ float bM;
  const int wv = tid >> 6, ln = tid & 63;
  float m = -1e30f;
  for (int i = tid * 4; i < 50048; i += 1024) {
    const f16x4 x = *(const f16x4*)(row + i);
    m = fmaxf(fmaxf(fmaxf(m, (float)x[0]), (float)x[1]), fmaxf((float)x[2], (float)x[3]));
  }
#pragma unroll
  for (int off = 32; off > 0; off >>= 1) m = fmaxf(m, __shfl_xor(m, off));
  if (ln == 0) ms[wv] = m;
  __syncthreads();
  if (tid == 0) bM = fmaxf(fmaxf(ms[0], ms[1]), fmaxf(ms[2], ms[3]));
  __syncthreads();
  const float M = bM;
  float s = 0.f;
  for (int i = tid * 4; i < 50048; i += 1024) {
    const f16x4 x = *(const f16x4*)(row + i);
    s += __expf((float)x[0] - M) + __expf((float)x[1] - M)
       + __expf((float)x[2] - M) + __expf((float)x[3] - M);
  }
#pragma unroll
  for (int off = 32; off > 0; off >>= 1) s += __shfl_xor(s, off);
  if (ln == 0) ss[wv] = s;
  __syncthreads();
  if (tid == 0) {
    row_m[b] = M;
    row_inv[b] = 1.f / (ss[0] + ss[1] + ss[2] + ss[3]);
  }
}

// ---------------- p = softmax(logits16) @ E  (split-K MFMA, atomic accumulate) ----------------
__global__ __launch_bounds__(256) void pgemm16_kernel(
    const _Float16* __restrict__ lg, const short* __restrict__ Et,
    const float* __restrict__ row_m, const float* __restrict__ row_inv,
    float* __restrict__ p_buf)
{
  const int tid = threadIdx.x;
  const int wave = tid >> 6, lane = tid & 63, lrow = lane & 15, lk8 = lane >> 4;
  const int m0 = blockIdx.y * 64;
  const int row = m0 + wave * 16 + lrow;
  const float rm = row_m[row], ri = row_inv[row];
  const _Float16* lp = lg + (size_t)row * 50048;
  const int kbeg = blockIdx.x * 1024;
  const int kend = (kbeg + 1024 <= 50048) ? kbeg + 1024 : 50048;
  f32x4 acc[8] = {{0,0,0,0},{0,0,0,0},{0,0,0,0},{0,0,0,0},
                  {0,0,0,0},{0,0,0,0},{0,0,0,0},{0,0,0,0}};
  for (int v0 = kbeg; v0 < kend; v0 += 32) {
    const int kb = v0 + lk8 * 8;
    const f16x8 v8 = *(const f16x8*)(lp + kb);
    bf16x8 afr;
#pragma unroll
    for (int j = 0; j < 8; ++j) afr[j] = f2bf(__expf((float)v8[j] - rm) * ri);
#pragma unroll
    for (int nt = 0; nt < 8; ++nt) {
      const bf16x8 bfr = *(const bf16x8*)(Et + (size_t)(nt * 16 + lrow) * 50048 + kb);
      acc[nt] = mfma16(afr, bfr, acc[nt]);
    }
  }
#pragma unroll
  for (int nt = 0; nt < 8; ++nt)
#pragma unroll
    for (int e2 = 0; e2 < 4; ++e2)
      atomicAdd(&p_buf[(size_t)(m0 + wave * 16 + lk8 * 4 + e2) * 128 + nt * 16 + lrow], acc[nt][e2]);
}

// ---------------- coef = concat(p, v) @ W_coef ----------------
__global__ __launch_bounds__(256) void coef_kernel(
    const float* __restrict__ p_buf, const float* __restrict__ v_buf,
    const float* __restrict__ W_coef, float* __restrict__ coef_buf)
{
  __shared__ float p_lds[4][128];
  const int g0 = blockIdx.x * 4;
  const int tid = threadIdx.x;
  for (int i = tid; i < 512; i += 256) ((float*)p_lds)[i] = p_buf[(size_t)g0 * 128 + i];
  __syncthreads();
  const int c = tid >> 1, dh = (tid & 1) * 4;
  float vg[4][8];
#pragma unroll
  for (int g = 0; g < 4; ++g) {
    const f32x4 va = *(const f32x4*)(v_buf + (size_t)(g0 + g) * 1024 + c * 8);
    const f32x4 vb = *(const f32x4*)(v_buf + (size_t)(g0 + g) * 1024 + c * 8 + 4);
    vg[g][0]=va[0]; vg[g][1]=va[1]; vg[g][2]=va[2]; vg[g][3]=va[3];
    vg[g][4]=vb[0]; vg[g][5]=vb[1]; vg[g][6]=vb[2]; vg[g][7]=vb[3];
  }
  const float* wc = W_coef + (size_t)c * 1088 + dh;
  f32x4 acc[4] = {{0,0,0,0},{0,0,0,0},{0,0,0,0},{0,0,0,0}};
  for (int dp = 0; dp < 128; ++dp) {
    const f32x4 w4 = *(const f32x4*)(wc + (size_t)dp * 8);
#pragma unroll
    for (int g = 0; g < 4; ++g) acc[g] += p_lds[g][dp] * w4;
  }
#pragma unroll
  for (int q = 0; q < 8; ++q) {
    const f32x4 w4 = *(const f32x4*)(wc + (size_t)(128 + q) * 8);
#pragma unroll
    for (int g = 0; g < 4; ++g) acc[g] += vg[g][q] * w4;
  }
#pragma unroll
  for (int g = 0; g < 4; ++g)
    *(f32x4*)(coef_buf + (size_t)(g0 + g) * 1024 + c * 8 + dh) = acc[g];
}

// ---------------- b (+)= sum_t e * (sum_d W * coef)  (512 thr, h-partitioned) ----------------
template<bool FIRST>
__global__ __launch_bounds__(512) void bupd_kernel(
    const float* __restrict__ coef_buf, const float* __restrict__ e_buf,
    const float* __restrict__ W, float* __restrict__ b_state)
{
  __shared__ float e_lds[4][128][4];
  const int g0 = blockIdx.x * 4;
  const int tid = threadIdx.x;
  for (int i = tid; i < 2048; i += 512) ((float*)e_lds)[i] = e_buf[(size_t)g0 * 512 + i];
  __syncthreads();
  const int half = tid >> 8;
  const int t8 = tid & 255;
  const int c = t8 >> 1, dh = (t8 & 1) * 4;
  f32x4 cf[4];
#pragma unroll
  for (int g = 0; g < 4; ++g)
    cf[g] = *(const f32x4*)(coef_buf + (size_t)(g0 + g) * 1024 + c * 8 + dh);
  const int hbeg = half * 64, hend = hbeg + 64;
  for (int h = hbeg; h < hend; ++h) {
    float accg[4] = {0.f, 0.f, 0.f, 0.f};
#pragma unroll
    for (int t4 = 0; t4 < 4; ++t4) {
      const f32x4 w4 = *(const f32x4*)(W + ((size_t)(h * 4 + t4) * 128 + c) * 8 + dh);
#pragma unroll
      for (int g = 0; g < 4; ++g) {
        const float d4 = w4[0]*cf[g][0] + w4[1]*cf[g][1] + w4[2]*cf[g][2] + w4[3]*cf[g][3];
        accg[g] += e_lds[g][h][t4] * d4;
      }
    }
#pragma unroll
    for (int g = 0; g < 4; ++g) {
      const float full = accg[g] + __shfl_xor(accg[g], 1);
      if ((tid & 1) == 0) {
        float* dst = &b_state[(size_t)(g0 + g) * 16384 + h * 128 + c];
        if (FIRST) *dst = full; else *dst += full;
      }
    }
  }
}

extern "C" void kernel_launch(void* const* d_in, const int* in_sizes, int n_in,
                              void* d_out, int out_size, void* d_ws, size_t ws_size,
                              hipStream_t stream) {
  const int* seq0 = (const int*)d_in[0];
  const int* seq1 = (const int*)d_in[1];
  const int* seq2 = (const int*)d_in[2];
  const int* seq3 = (const int*)d_in[3];
  const float* item_emb = (const float*)d_in[4];
  const float* Wih = (const float*)d_in[5];
  const float* Whh = (const float*)d_in[6];
  const float* bih = (const float*)d_in[7];
  const float* bhh = (const float*)d_in[8];
  const float* W = (const float*)d_in[9];
  const float* w_scale = (const float*)d_in[10];
  const float* bias_vec = (const float*)d_in[11];
  const float* alpha = (const float*)d_in[12];
  const float* W_coef = (const float*)d_in[13];
  float* out = (float*)d_out;
  _Float16* lg16 = (_Float16*)d_out;    // iter logits (51.25 MB) alias in d_out

  char* ws = (char*)d_ws;
  float* e_buf    = (float*)(ws);                 // 1,048,576 B
  float* b_state  = (float*)(ws + 1048576);       // 33,554,432 B
  float* v_buf    = (float*)(ws + 34603008);      // 2,097,152 B
  float* vn_buf   = (float*)(ws + 36700160);      // 262,144 B
  float* p_buf    = (float*)(ws + 36962304);      // 262,144 B
  float* coef_buf = (float*)(ws + 37224448);      // 2,097,152 B
  float* row_m    = (float*)(ws + 39321600);      // 2,048 B
  float* row_inv  = (float*)(ws + 39323648);      // 2,048 B
  short* Ebf      = (short*)(ws + 39325696);      // 12,800,256 B
  short* Et       = (short*)(ws + 52125952);      // 12,812,288 B  (total ~64.9 MB)

  // gi scratch: t50 behaviors (59.0 MB) overlaps [b_state..Et) -- lifetime ends
  // before cast_ebf/build_et below; b_state is first written by bupd<FIRST>.
  // click gi (78.6 MB) lives in d_out until the first logits16 write.
  unsigned short* gi_t50   = (unsigned short*)(ws + 1048576);
  unsigned short* gi_click = (unsigned short*)d_out;

  gi_gemm_kernel<<<dim3(700), 512, 0, stream>>>(seq0, seq1, seq2, seq3, item_emb, Wih,
                                                gi_t50, gi_click);
  gru_rec5_kernel<<<dim3(512), 256, 0, stream>>>(Whh, bih, bhh, gi_t50, gi_click, e_buf);
  cast_ebf<<<dim3(25001), 256, 0, stream>>>(item_emb, Ebf);
  build_et<<<dim3(782), 256, 0, stream>>>(item_emb, Et);

  // iter 0 (b = 0 implicitly)
  caps_v_kernel<true><<<dim3(128), 512, 0, stream>>>(b_state, e_buf, W, w_scale, bias_vec,
                                                     alpha, v_buf, vn_buf);
  logits16_kernel<<<dim3(782, 4), 512, 0, stream>>>(vn_buf, Ebf, lg16);
  rowstats16_kernel<<<dim3(512), 256, 0, stream>>>(lg16, row_m, row_inv);
  hipMemsetAsync(p_buf, 0, 262144, stream);
  pgemm16_kernel<<<dim3(49, 8), 256, 0, stream>>>(lg16, Et, row_m, row_inv, p_buf);
  coef_kernel<<<dim3(128), 256, 0, stream>>>(p_buf, v_buf, W_coef, coef_buf);
  bupd_kernel<true><<<dim3(128), 512, 0, stream>>>(coef_buf, e_buf, W, b_state);
  // iter 1
  caps_v_kernel<false><<<dim3(128), 512, 0, stream>>>(b_state, e_buf, W, w_scale, bias_vec,
                                                      alpha, v_buf, vn_buf);
  logits16_kernel<<<dim3(782, 4), 512, 0, stream>>>(vn_buf, Ebf, lg16);
  rowstats16_kernel<<<dim3(512), 256, 0, stream>>>(lg16, row_m, row_inv);
  hipMemsetAsync(p_buf, 0, 262144, stream);
  pgemm16_kernel<<<dim3(49, 8), 256, 0, stream>>>(lg16, Et, row_m, row_inv, p_buf);
  coef_kernel<<<dim3(128), 256, 0, stream>>>(p_buf, v_buf, W_coef, coef_buf);
  bupd_kernel<false><<<dim3(128), 512, 0, stream>>>(coef_buf, e_buf, W, b_state);
  // final
  caps_v_kernel<false><<<dim3(128), 512, 0, stream>>>(b_state, e_buf, W, w_scale, bias_vec,
                                                      alpha, v_buf, vn_buf);
  logits_kernel<<<dim3(782, 4), 512, 0, stream>>>(vn_buf, Ebf, out);
}

// Round 8
// 789.416 us; speedup vs baseline: 1.7483x; 1.2927x over previous
//
#include <hip/hip_runtime.h>
#include <math.h>

typedef __attribute__((ext_vector_type(8))) short bf16x8;
typedef __attribute__((ext_vector_type(4))) float f32x4;
typedef __attribute__((ext_vector_type(2))) float f32x2;
typedef __attribute__((ext_vector_type(4))) unsigned short u16x4;
typedef __attribute__((ext_vector_type(4))) _Float16 f16x4;
typedef __attribute__((ext_vector_type(8))) _Float16 f16x8;

static __device__ __forceinline__ short f2bf(float f) {
  unsigned u = __builtin_bit_cast(unsigned, f);
  u += 0x7fffu + ((u >> 16) & 1u);
  return (short)(u >> 16);
}
static __device__ __forceinline__ float bf2f(unsigned short s) {
  unsigned u = ((unsigned)s) << 16;
  return __builtin_bit_cast(float, u);
}
static __device__ __forceinline__ f32x4 mfma16(bf16x8 a, bf16x8 b, f32x4 c) {
  return __builtin_amdgcn_mfma_f32_16x16x32_bf16(a, b, c, 0, 0, 0);
}
static __device__ __forceinline__ bf16x8 pack8v(f32x4 a, f32x4 b) {
  bf16x8 r;
  r[0]=f2bf(a[0]); r[1]=f2bf(a[1]); r[2]=f2bf(a[2]); r[3]=f2bf(a[3]);
  r[4]=f2bf(b[0]); r[5]=f2bf(b[1]); r[6]=f2bf(b[2]); r[7]=f2bf(b[3]);
  return r;
}
static __device__ __forceinline__ float fastrcp(float x) {
  float r;
  asm("v_rcp_f32_e32 %0, %1" : "=v"(r) : "v"(x));
  return r;
}
static __device__ __forceinline__ float dot4(f32x4 a, f32x4 b) {
  return a[0]*b[0] + a[1]*b[1] + a[2]*b[2] + a[3]*b[3];
}

#define LGKM_BARRIER() do {                                   \
    asm volatile("s_waitcnt lgkmcnt(0)" ::: "memory");        \
    __builtin_amdgcn_s_barrier();                             \
    __builtin_amdgcn_sched_barrier(0);                        \
  } while (0)

// ---------------- gi = x @ Wih^T, compact 4-row quad tiles ----------------
__global__ __launch_bounds__(512) void gi_gemm_kernel(
    const int* __restrict__ seq0, const int* __restrict__ seq1,
    const int* __restrict__ seq2, const int* __restrict__ seq3,
    const float* __restrict__ item_emb, const float* __restrict__ Wih,
    unsigned short* __restrict__ gi_t50, unsigned short* __restrict__ gi_click)
{
  const int b = blockIdx.x;
  int beh, tile0;
  if (b < 100)      { beh = 0; tile0 = b * 16; }
  else if (b < 200) { beh = 1; tile0 = (b - 100) * 16; }
  else if (b < 300) { beh = 2; tile0 = (b - 200) * 16; }
  else              { beh = 3; tile0 = (b - 300) * 16; }
  const int T = (beh == 3) ? 200 : 50;
  const int* seq = (beh == 0) ? seq0 : (beh == 1) ? seq1 : (beh == 2) ? seq2 : seq3;
  unsigned short* gibase = (beh == 3) ? gi_click : (gi_t50 + (size_t)beh * 9830400);

  const int tid = threadIdx.x;
  const int wave = tid >> 6, lane = tid & 63, lrow = lane & 15, lk8 = lane >> 4;
  const int bcol = wave * 16 + lrow;

  bf16x8 wif[3][4];
  const float* WihB = Wih + (size_t)beh * 384 * 128;
#pragma unroll
  for (int g = 0; g < 3; ++g) {
    const int wr = g * 128 + bcol;
#pragma unroll
    for (int kt = 0; kt < 4; ++kt) {
      const int k0 = kt * 32 + lk8 * 8;
      f32x4 a0 = *(const f32x4*)(WihB + (size_t)wr * 128 + k0);
      f32x4 a1 = *(const f32x4*)(WihB + (size_t)wr * 128 + k0 + 4);
      wif[g][kt] = pack8v(a0, a1);
    }
  }

  __shared__ short xt[16][132];
  const int gj = tid >> 5;
  const int gc = (tid & 31) * 4;

  for (int ti = 0; ti < 16; ++ti) {
    const int tile = tile0 + ti;
    const int r0blk = tile / T;
    const int t = tile - r0blk * T;
    {
      const int sidx = seq[(size_t)(r0blk * 16 + gj) * T + t];
      const f32x4 xv = *(const f32x4*)(item_emb + (size_t)sidx * 128 + gc);
      xt[gj][gc]     = f2bf(xv[0]);
      xt[gj][gc + 1] = f2bf(xv[1]);
      xt[gj][gc + 2] = f2bf(xv[2]);
      xt[gj][gc + 3] = f2bf(xv[3]);
    }
    __syncthreads();
    bf16x8 ax[4];
#pragma unroll
    for (int kt = 0; kt < 4; ++kt)
      ax[kt] = *(const bf16x8*)&xt[lrow][kt * 32 + lk8 * 8];
    f32x4 acc[3] = {{0,0,0,0},{0,0,0,0},{0,0,0,0}};
#pragma unroll
    for (int kt = 0; kt < 4; ++kt) {
      acc[0] = mfma16(ax[kt], wif[0][kt], acc[0]);
      acc[1] = mfma16(ax[kt], wif[1][kt], acc[1]);
      acc[2] = mfma16(ax[kt], wif[2][kt], acc[2]);
    }
    unsigned short* base = gibase + ((size_t)(r0blk * 4 + lk8) * T + t) * 1536;
    unsigned short* dst = base + bcol * 4;
#pragma unroll
    for (int g = 0; g < 3; ++g) {
      u16x4 o;
      o[0] = (unsigned short)f2bf(acc[g][0]);
      o[1] = (unsigned short)f2bf(acc[g][1]);
      o[2] = (unsigned short)f2bf(acc[g][2]);
      o[3] = (unsigned short)f2bf(acc[g][3]);
      *(u16x4*)(dst + g * 512) = o;
    }
    __syncthreads();
  }
}

// ---------------- GRU recurrence (blocks 0..511) + Et-transpose workers (512..639) ----------------
__global__ __launch_bounds__(256, 2) void gru_rec5w_kernel(
    const float* __restrict__ Whh, const float* __restrict__ bih,
    const float* __restrict__ bhh,
    const unsigned short* __restrict__ gi_t50,
    const unsigned short* __restrict__ gi_click,
    const float* __restrict__ item_emb, short* __restrict__ Et,
    float* __restrict__ e_out)
{
  __shared__ short h0[16][140];
  __shared__ short h1[16][140];
  __shared__ float ttile[64][36];
  const int tid = threadIdx.x;

  if (blockIdx.x >= 512) {
    // --- Et workers: build E^T bf16 [128][50048] in d_out tail, hidden in click tail
    const int wb = blockIdx.x - 512;     // 0..127
    for (int unit = wb; unit < 3128; unit += 128) {
      const int vt = unit >> 2, kp = unit & 3;
      const int v0 = vt * 64, ks = kp * 32;
      const int r = tid >> 2, cc = (tid & 3) * 8;
      f32x4 x0 = {0,0,0,0}, x1 = {0,0,0,0};
      if (v0 + r < 50001) {
        x0 = *(const f32x4*)(item_emb + (size_t)(v0 + r) * 128 + ks + cc);
        x1 = *(const f32x4*)(item_emb + (size_t)(v0 + r) * 128 + ks + cc + 4);
      }
      *(f32x4*)&ttile[r][cc] = x0;
      *(f32x4*)&ttile[r][cc + 4] = x1;
      __syncthreads();
      const int k = tid >> 3, vs = (tid & 7) * 8;
#pragma unroll
      for (int j = 0; j < 8; j += 4) {
        u16x4 o;
        o[0] = (unsigned short)f2bf(ttile[vs + j][k]);
        o[1] = (unsigned short)f2bf(ttile[vs + j + 1][k]);
        o[2] = (unsigned short)f2bf(ttile[vs + j + 2][k]);
        o[3] = (unsigned short)f2bf(ttile[vs + j + 3][k]);
        *(u16x4*)((unsigned short*)Et + (size_t)(ks + k) * 50048 + v0 + vs + j) = o;
      }
      __syncthreads();
    }
    return;
  }

  const int beh = blockIdx.x >> 7;
  const int qt = blockIdx.x & 127;
  const int T = (beh == 3) ? 200 : 50;
  const unsigned short* gib =
      ((beh == 3) ? gi_click : (gi_t50 + (size_t)beh * 9830400)) + (size_t)qt * T * 1536;

  const int w = tid >> 6;
  const int lane = tid & 63;
  const int lrow = lane & 15;
  const int lk8 = lane >> 4;
  const int col0 = w * 32 + lrow;
  const int col1 = col0 + 16;

  bf16x8 whf[3][2][4];
  const float* WhhB = Whh + (size_t)beh * 384 * 128;
#pragma unroll
  for (int g = 0; g < 3; ++g) {
#pragma unroll
    for (int ct = 0; ct < 2; ++ct) {
      const int wr = g * 128 + (ct ? col1 : col0);
#pragma unroll
      for (int kt = 0; kt < 4; ++kt) {
        const int k0 = kt * 32 + lk8 * 8;
        f32x4 b0 = *(const f32x4*)(WhhB + (size_t)wr * 128 + k0);
        f32x4 b1 = *(const f32x4*)(WhhB + (size_t)wr * 128 + k0 + 4);
        whf[g][ct][kt] = pack8v(b0, b1);
      }
    }
  }
  float bR[2], bZ[2], bN[2], bHN[2];
#pragma unroll
  for (int ct = 0; ct < 2; ++ct) {
    const int c = ct ? col1 : col0;
    bR[ct]  = bih[beh * 384 + c] + bhh[beh * 384 + c];
    bZ[ct]  = bih[beh * 384 + 128 + c] + bhh[beh * 384 + 128 + c];
    bN[ct]  = bih[beh * 384 + 256 + c];
    bHN[ct] = bhh[beh * 384 + 256 + c];
  }

  for (int i = tid; i < 16 * 140; i += 256) { ((short*)h0)[i] = 0; ((short*)h1)[i] = 0; }
  float hreg[2] = {0.f, 0.f};
  __syncthreads();

  const unsigned short* gp0 = gib + col0 * 4 + lk8;
  const unsigned short* gp1 = gib + col1 * 4 + lk8;

  unsigned short ga[30], gb[30];

#define LOAD_CHUNK(BUF, C0) do {                                              \
    _Pragma("unroll")                                                         \
    for (int _s = 0; _s < 5; ++_s) {                                          \
      const size_t _o = (size_t)((C0) + _s) * 1536;                           \
      _Pragma("unroll")                                                       \
      for (int _g = 0; _g < 3; ++_g) {                                        \
        BUF[_s * 6 + 0 * 3 + _g] = gp0[_o + _g * 512];                        \
        BUF[_s * 6 + 1 * 3 + _g] = gp1[_o + _g * 512];                        \
      }                                                                       \
    }                                                                         \
  } while (0)

  short (*hin)[140] = h0;
  short (*hout)[140] = h1;

#define STEP(BUF, S) do {                                                     \
    bf16x8 ah[4];                                                             \
    _Pragma("unroll")                                                         \
    for (int kt = 0; kt < 4; ++kt)                                            \
      ah[kt] = *(const bf16x8*)&hin[lrow][kt * 32 + lk8 * 8];                 \
    f32x4 hr_[2], hz_[2], hn_[2];                                             \
    _Pragma("unroll")                                                         \
    for (int ct = 0; ct < 2; ++ct) {                                          \
      hr_[ct] = (f32x4){0,0,0,0}; hz_[ct] = (f32x4){0,0,0,0}; hn_[ct] = (f32x4){0,0,0,0}; \
      _Pragma("unroll")                                                       \
      for (int kt = 0; kt < 4; ++kt) {                                        \
        hr_[ct] = mfma16(ah[kt], whf[0][ct][kt], hr_[ct]);                    \
        hz_[ct] = mfma16(ah[kt], whf[1][ct][kt], hz_[ct]);                    \
        hn_[ct] = mfma16(ah[kt], whf[2][ct][kt], hn_[ct]);                    \
      }                                                                       \
    }                                                                         \
    _Pragma("unroll")                                                         \
    for (int ct = 0; ct < 2; ++ct) {                                          \
      const float xr = bf2f(BUF[(S)*6 + ct*3 + 0]) + bR[ct] + hr_[ct][0];     \
      const float xz = bf2f(BUF[(S)*6 + ct*3 + 1]) + bZ[ct] + hz_[ct][0];     \
      const float ea = __expf(-xr);                                           \
      const float eb = __expf(-xz);                                           \
      const float pa = 1.f + ea, pb = 1.f + eb;                               \
      const float rd = fastrcp(pa * pb);                                      \
      const float rr = pb * rd;                                               \
      const float zz = pa * rd;                                               \
      const float tn = bf2f(BUF[(S)*6 + ct*3 + 2]) + bN[ct] + rr * (hn_[ct][0] + bHN[ct]); \
      const float tt = __expf(-2.f * tn);                                     \
      const float nn = (1.f - tt) * fastrcp(1.f + tt);                        \
      hreg[ct] = nn + zz * (hreg[ct] - nn);                                   \
      hout[lk8 * 4][ct ? col1 : col0] = f2bf(hreg[ct]);                       \
    }                                                                         \
    LGKM_BARRIER();                                                           \
    short (*_tmp)[140] = hin; hin = hout; hout = _tmp;                        \
  } while (0)

  LOAD_CHUNK(ga, 0);
  for (int c = 0; c < T; c += 10) {
    if (c + 5 < T) LOAD_CHUNK(gb, c + 5);
    STEP(ga, 0); STEP(ga, 1); STEP(ga, 2); STEP(ga, 3); STEP(ga, 4);
    if (c + 10 < T) LOAD_CHUNK(ga, c + 10);
    STEP(gb, 0); STEP(gb, 1); STEP(gb, 2); STEP(gb, 3); STEP(gb, 4);
  }
#undef STEP
#undef LOAD_CHUNK

#pragma unroll
  for (int ct = 0; ct < 2; ++ct)
    e_out[(size_t)(qt * 4 + lk8) * 512 + (ct ? col1 : col0) * 4 + beh] = hreg[ct];
}

// ---------------- route: fused b-update + softmax(c) + v + vn ----------------
// MODE 0: cv = 1/128 (no coef, no b). MODE 1: b = delta(coef), write b. MODE 2: b = b_old + delta, no write.
template<int MODE>
__global__ __launch_bounds__(256, 1) void route_kernel(
    const float* __restrict__ b_old, float* __restrict__ b_new,
    const float* __restrict__ e_buf, const float* __restrict__ W,
    const float* __restrict__ coef_buf,
    const float* __restrict__ w_scale, const float* __restrict__ bias_vec,
    const float* __restrict__ alpha,
    float* __restrict__ v_buf, float* __restrict__ vn_buf)
{
  __shared__ float e_lds[4][128][4];
  __shared__ float vacc[4][4][128][8];   // [wave][g][c][d] = 64 KB
  const int g0 = blockIdx.x * 4;
  const int tid = threadIdx.x;
  const int wv = tid >> 6, ln = tid & 63;
  const int c0 = ln * 2;
  for (int i = tid; i < 2048; i += 256) ((float*)e_lds)[i] = e_buf[(size_t)g0 * 512 + i];

  f32x4 cf[4][2][2];
  if (MODE != 0) {
#pragma unroll
    for (int g = 0; g < 4; ++g)
#pragma unroll
      for (int cc = 0; cc < 2; ++cc) {
        cf[g][cc][0] = *(const f32x4*)(coef_buf + (size_t)(g0 + g) * 1024 + (c0 + cc) * 8);
        cf[g][cc][1] = *(const f32x4*)(coef_buf + (size_t)(g0 + g) * 1024 + (c0 + cc) * 8 + 4);
      }
  }
  __syncthreads();

  f32x4 av[4][2][2];
#pragma unroll
  for (int g = 0; g < 4; ++g)
#pragma unroll
    for (int cc = 0; cc < 2; ++cc) { av[g][cc][0] = (f32x4){0,0,0,0}; av[g][cc][1] = (f32x4){0,0,0,0}; }

  const int hbeg = wv * 32;
  for (int h = hbeg; h < hbeg + 32; ++h) {
    f32x4 wr[4][2][2];
#pragma unroll
    for (int t = 0; t < 4; ++t) {
      const float* wp = W + ((size_t)(h * 4 + t) * 128 + c0) * 8;
      wr[t][0][0] = *(const f32x4*)(wp);
      wr[t][0][1] = *(const f32x4*)(wp + 4);
      wr[t][1][0] = *(const f32x4*)(wp + 8);
      wr[t][1][1] = *(const f32x4*)(wp + 12);
    }
    f32x2 bo[4];
    if (MODE == 2) {
#pragma unroll
      for (int g = 0; g < 4; ++g)
        bo[g] = *(const f32x2*)(b_old + (size_t)(g0 + g) * 16384 + h * 128 + c0);
    }
#pragma unroll
    for (int g = 0; g < 4; ++g) {
      const f32x4 ev = *(const f32x4*)&e_lds[g][h][0];
      f32x4 u[2][2];
#pragma unroll
      for (int cc = 0; cc < 2; ++cc)
#pragma unroll
        for (int dd = 0; dd < 2; ++dd)
          u[cc][dd] = ev[0]*wr[0][cc][dd] + ev[1]*wr[1][cc][dd]
                    + ev[2]*wr[2][cc][dd] + ev[3]*wr[3][cc][dd];
      float cv0, cv1;
      if (MODE == 0) {
        cv0 = 0.0078125f; cv1 = 0.0078125f;
      } else {
        float b0 = dot4(u[0][0], cf[g][0][0]) + dot4(u[0][1], cf[g][0][1]);
        float b1 = dot4(u[1][0], cf[g][1][0]) + dot4(u[1][1], cf[g][1][1]);
        if (MODE == 2) { b0 += bo[g][0]; b1 += bo[g][1]; }
        if (MODE == 1)
          *(f32x2*)(b_new + (size_t)(g0 + g) * 16384 + h * 128 + c0) = (f32x2){b0, b1};
        float m = fmaxf(b0, b1);
#pragma unroll
        for (int off = 32; off > 0; off >>= 1) m = fmaxf(m, __shfl_xor(m, off));
        const float e0 = __expf(b0 - m), e1 = __expf(b1 - m);
        float s = e0 + e1;
#pragma unroll
        for (int off = 32; off > 0; off >>= 1) s += __shfl_xor(s, off);
        const float inv = 1.f / s;
        cv0 = e0 * inv; cv1 = e1 * inv;
      }
      av[g][0][0] += cv0 * u[0][0]; av[g][0][1] += cv0 * u[0][1];
      av[g][1][0] += cv1 * u[1][0]; av[g][1][1] += cv1 * u[1][1];
    }
  }
#pragma unroll
  for (int g = 0; g < 4; ++g)
#pragma unroll
    for (int cc = 0; cc < 2; ++cc) {
      *(f32x4*)&vacc[wv][g][c0 + cc][0] = av[g][cc][0];
      *(f32x4*)&vacc[wv][g][c0 + cc][4] = av[g][cc][1];
    }
  __syncthreads();

  const float al = alpha[0];
  const int rg = tid >> 6;
  const int rc = (tid & 63) * 2;
#pragma unroll
  for (int cc = 0; cc < 2; ++cc) {
    const int c = rc + cc;
    f32x4 s0 = *(const f32x4*)&vacc[0][rg][c][0];
    f32x4 s1 = *(const f32x4*)&vacc[0][rg][c][4];
#pragma unroll
    for (int wq = 1; wq < 4; ++wq) {
      s0 += *(const f32x4*)&vacc[wq][rg][c][0];
      s1 += *(const f32x4*)&vacc[wq][rg][c][4];
    }
    s0 *= al; s1 *= al;
    *(f32x4*)(v_buf + (size_t)(g0 + rg) * 1024 + c * 8) = s0;
    *(f32x4*)(v_buf + (size_t)(g0 + rg) * 1024 + c * 8 + 4) = s1;
    const float ss = dot4(s0, s0) + dot4(s1, s1);
    vn_buf[(g0 + rg) * 128 + c] = sqrtf(ss) * w_scale[c] + bias_vec[c];
  }
}

// ---------------- iter logits fp16 (stride 50048) + per-block partial row stats ----------------
__global__ __launch_bounds__(512) void logits16s_kernel(
    const float* __restrict__ vn, const float* __restrict__ E,
    _Float16* __restrict__ out16, float* __restrict__ pm, float* __restrict__ ps)
{
  __shared__ short et[64][136];
  const int n0 = blockIdx.x * 64;
  const int tid = threadIdx.x;
  const int wave = tid >> 6, lane = tid & 63, lrow = lane & 15, lk8 = lane >> 4;
  {
    const int r = tid >> 3, ks = (tid & 7) * 16;
    const int v = n0 + r;
    f32x4 a = {0,0,0,0}, b = {0,0,0,0}, c = {0,0,0,0}, d = {0,0,0,0};
    if (v < 50001) {
      const float* p = E + (size_t)v * 128 + ks;
      a = *(const f32x4*)p; b = *(const f32x4*)(p + 4);
      c = *(const f32x4*)(p + 8); d = *(const f32x4*)(p + 12);
    }
    *(bf16x8*)&et[r][ks] = pack8v(a, b);
    *(bf16x8*)&et[r][ks + 8] = pack8v(c, d);
  }
  __syncthreads();
  for (int mb = 0; mb < 4; ++mb) {
    const int m0 = mb * 128;
    const int arow = m0 + wave * 16 + lrow;
    bf16x8 afr[4];
#pragma unroll
    for (int kt = 0; kt < 4; ++kt) {
      const float* p = vn + (size_t)arow * 128 + kt * 32 + lk8 * 8;
      afr[kt] = pack8v(*(const f32x4*)p, *(const f32x4*)(p + 4));
    }
    f32x4 acc[4] = {{0,0,0,0},{0,0,0,0},{0,0,0,0},{0,0,0,0}};
#pragma unroll
    for (int kt = 0; kt < 4; ++kt) {
#pragma unroll
      for (int nt = 0; nt < 4; ++nt) {
        const bf16x8 bfr = *(const bf16x8*)&et[nt * 16 + lrow][kt * 32 + lk8 * 8];
        acc[nt] = mfma16(afr[kt], bfr, acc[nt]);
      }
    }
    // store fp16 + per-row partial stats over this block's 64 cols (fp16-consistent)
    float xv[4][4];   // [e2][nt]
#pragma unroll
    for (int nt = 0; nt < 4; ++nt) {
      const int col = n0 + nt * 16 + lrow;
      const int row = m0 + wave * 16 + lk8 * 4;
#pragma unroll
      for (int e2 = 0; e2 < 4; ++e2) {
        const float v = (col < 50001) ? acc[nt][e2] : -60000.f;
        const _Float16 h16 = (_Float16)v;
        out16[(size_t)(row + e2) * 50048 + col] = h16;
        xv[e2][nt] = (float)h16;
      }
    }
#pragma unroll
    for (int e2 = 0; e2 < 4; ++e2) {
      float lm = fmaxf(fmaxf(xv[e2][0], xv[e2][1]), fmaxf(xv[e2][2], xv[e2][3]));
#pragma unroll
      for (int off = 8; off > 0; off >>= 1) lm = fmaxf(lm, __shfl_xor(lm, off));
      float s = __expf(xv[e2][0] - lm) + __expf(xv[e2][1] - lm)
              + __expf(xv[e2][2] - lm) + __expf(xv[e2][3] - lm);
#pragma unroll
      for (int off = 8; off > 0; off >>= 1) s += __shfl_xor(s, off);
      if (lrow == 0) {
        const int row = m0 + wave * 16 + lk8 * 4 + e2;
        pm[(size_t)row * 784 + blockIdx.x] = lm;
        ps[(size_t)row * 784 + blockIdx.x] = s;
      }
    }
  }
}

// ---------------- combine partial stats -> row max / inv-sum ----------------
__global__ __launch_bounds__(256) void rowstats_p_kernel(
    const float* __restrict__ pm, const float* __restrict__ ps,
    float* __restrict__ row_m, float* __restrict__ row_inv)
{
  const int b = blockIdx.x;
  const int tid = threadIdx.x;
  const float* pmr = pm + (size_t)b * 784;
  const float* psr = ps + (size_t)b * 784;
  __shared__ float sm[4], ssum[4];
  const int wv = tid >> 6, ln = tid & 63;
  float m = -1e30f;
  for (int i = tid; i < 782; i += 256) m = fmaxf(m, pmr[i]);
#pragma unroll
  for (int off = 32; off > 0; off >>= 1) m = fmaxf(m, __shfl_xor(m, off));
  if (ln == 0) sm[wv] = m;
  __syncthreads();
  const float M = fmaxf(fmaxf(sm[0], sm[1]), fmaxf(sm[2], sm[3]));
  float s = 0.f;
  for (int i = tid; i < 782; i += 256) s += psr[i] * __expf(pmr[i] - M);
#pragma unroll
  for (int off = 32; off > 0; off >>= 1) s += __shfl_xor(s, off);
  if (ln == 0) ssum[wv] = s;
  __syncthreads();
  if (tid == 0) {
    row_m[b] = M;
    row_inv[b] = 1.f / (ssum[0] + ssum[1] + ssum[2] + ssum[3]);
  }
}

// ---------------- p = softmax(logits16) @ E  (split-K MFMA, atomic accumulate) ----------------
__global__ __launch_bounds__(256) void pgemm16_kernel(
    const _Float16* __restrict__ lg, const short* __restrict__ Et,
    const float* __restrict__ row_m, const float* __restrict__ row_inv,
    float* __restrict__ p_buf)
{
  const int tid = threadIdx.x;
  const int wave = tid >> 6, lane = tid & 63, lrow = lane & 15, lk8 = lane >> 4;
  const int m0 = blockIdx.y * 64;
  const int row = m0 + wave * 16 + lrow;
  const float rm = row_m[row], ri = row_inv[row];
  const _Float16* lp = lg + (size_t)row * 50048;
  const int kbeg = blockIdx.x * 1024;
  const int kend = (kbeg + 1024 <= 50048) ? kbeg + 1024 : 50048;
  f32x4 acc[8] = {{0,0,0,0},{0,0,0,0},{0,0,0,0},{0,0,0,0},
                  {0,0,0,0},{0,0,0,0},{0,0,0,0},{0,0,0,0}};
  for (int v0 = kbeg; v0 < kend; v0 += 32) {
    const int kb = v0 + lk8 * 8;
    const f16x8 v8 = *(const f16x8*)(lp + kb);
    bf16x8 afr;
#pragma unroll
    for (int j = 0; j < 8; ++j) afr[j] = f2bf(__expf((float)v8[j] - rm) * ri);
#pragma unroll
    for (int nt = 0; nt < 8; ++nt) {
      const bf16x8 bfr = *(const bf16x8*)(Et + (size_t)(nt * 16 + lrow) * 50048 + kb);
      acc[nt] = mfma16(afr, bfr, acc[nt]);
    }
  }
#pragma unroll
  for (int nt = 0; nt < 8; ++nt)
#pragma unroll
    for (int e2 = 0; e2 < 4; ++e2)
      atomicAdd(&p_buf[(size_t)(m0 + wave * 16 + lk8 * 4 + e2) * 128 + nt * 16 + lrow], acc[nt][e2]);
}

// ---------------- coef = concat(p, v) @ W_coef ----------------
__global__ __launch_bounds__(256) void coef_kernel(
    const float* __restrict__ p_buf, const float* __restrict__ v_buf,
    const float* __restrict__ W_coef, float* __restrict__ coef_buf)
{
  __shared__ float p_lds[4][128];
  const int g0 = blockIdx.x * 4;
  const int tid = threadIdx.x;
  for (int i = tid; i < 512; i += 256) ((float*)p_lds)[i] = p_buf[(size_t)g0 * 128 + i];
  __syncthreads();
  const int c = tid >> 1, dh = (tid & 1) * 4;
  float vg[4][8];
#pragma unroll
  for (int g = 0; g < 4; ++g) {
    const f32x4 va = *(const f32x4*)(v_buf + (size_t)(g0 + g) * 1024 + c * 8);
    const f32x4 vb = *(const f32x4*)(v_buf + (size_t)(g0 + g) * 1024 + c * 8 + 4);
    vg[g][0]=va[0]; vg[g][1]=va[1]; vg[g][2]=va[2]; vg[g][3]=va[3];
    vg[g][4]=vb[0]; vg[g][5]=vb[1]; vg[g][6]=vb[2]; vg[g][7]=vb[3];
  }
  const float* wc = W_coef + (size_t)c * 1088 + dh;
  f32x4 acc[4] = {{0,0,0,0},{0,0,0,0},{0,0,0,0},{0,0,0,0}};
  for (int dp = 0; dp < 128; ++dp) {
    const f32x4 w4 = *(const f32x4*)(wc + (size_t)dp * 8);
#pragma unroll
    for (int g = 0; g < 4; ++g) acc[g] += p_lds[g][dp] * w4;
  }
#pragma unroll
  for (int q = 0; q < 8; ++q) {
    const f32x4 w4 = *(const f32x4*)(wc + (size_t)(128 + q) * 8);
#pragma unroll
    for (int g = 0; g < 4; ++g) acc[g] += vg[g][q] * w4;
  }
#pragma unroll
  for (int g = 0; g < 4; ++g)
    *(f32x4*)(coef_buf + (size_t)(g0 + g) * 1024 + c * 8 + dh) = acc[g];
}

// ---------------- final logits fp32 into d_out (stages from fp32 item_emb) ----------------
__global__ __launch_bounds__(512) void logits32_kernel(
    const float* __restrict__ vn, const float* __restrict__ E,
    float* __restrict__ out)
{
  __shared__ short et[64][136];
  const int n0 = blockIdx.x * 64;
  const int tid = threadIdx.x;
  const int wave = tid >> 6, lane = tid & 63, lrow = lane & 15, lk8 = lane >> 4;
  {
    const int r = tid >> 3, ks = (tid & 7) * 16;
    const int v = n0 + r;
    f32x4 a = {0,0,0,0}, b = {0,0,0,0}, c = {0,0,0,0}, d = {0,0,0,0};
    if (v < 50001) {
      const float* p = E + (size_t)v * 128 + ks;
      a = *(const f32x4*)p; b = *(const f32x4*)(p + 4);
      c = *(const f32x4*)(p + 8); d = *(const f32x4*)(p + 12);
    }
    *(bf16x8*)&et[r][ks] = pack8v(a, b);
    *(bf16x8*)&et[r][ks + 8] = pack8v(c, d);
  }
  __syncthreads();
  for (int mb = 0; mb < 4; ++mb) {
    const int m0 = mb * 128;
    const int arow = m0 + wave * 16 + lrow;
    bf16x8 afr[4];
#pragma unroll
    for (int kt = 0; kt < 4; ++kt) {
      const float* p = vn + (size_t)arow * 128 + kt * 32 + lk8 * 8;
      afr[kt] = pack8v(*(const f32x4*)p, *(const f32x4*)(p + 4));
    }
    f32x4 acc[4] = {{0,0,0,0},{0,0,0,0},{0,0,0,0},{0,0,0,0}};
#pragma unroll
    for (int kt = 0; kt < 4; ++kt) {
#pragma unroll
      for (int nt = 0; nt < 4; ++nt) {
        const bf16x8 bfr = *(const bf16x8*)&et[nt * 16 + lrow][kt * 32 + lk8 * 8];
        acc[nt] = mfma16(afr[kt], bfr, acc[nt]);
      }
    }
#pragma unroll
    for (int nt = 0; nt < 4; ++nt) {
      const int col = n0 + nt * 16 + lrow;
      if (col < 50001) {
        const int row = m0 + wave * 16 + lk8 * 4;
#pragma unroll
        for (int e2 = 0; e2 < 4; ++e2)
          out[(size_t)(row + e2) * 50001 + col] = acc[nt][e2];
      }
    }
  }
}

extern "C" void kernel_launch(void* const* d_in, const int* in_sizes, int n_in,
                              void* d_out, int out_size, void* d_ws, size_t ws_size,
                              hipStream_t stream) {
  const int* seq0 = (const int*)d_in[0];
  const int* seq1 = (const int*)d_in[1];
  const int* seq2 = (const int*)d_in[2];
  const int* seq3 = (const int*)d_in[3];
  const float* item_emb = (const float*)d_in[4];
  const float* Wih = (const float*)d_in[5];
  const float* Whh = (const float*)d_in[6];
  const float* bih = (const float*)d_in[7];
  const float* bhh = (const float*)d_in[8];
  const float* W = (const float*)d_in[9];
  const float* w_scale = (const float*)d_in[10];
  const float* bias_vec = (const float*)d_in[11];
  const float* alpha = (const float*)d_in[12];
  const float* W_coef = (const float*)d_in[13];
  float* out = (float*)d_out;
  _Float16* lg16 = (_Float16*)d_out;                       // iter logits, 51.25 MB

  char* ws = (char*)d_ws;
  float* e_buf    = (float*)(ws);                 // 1 MB
  float* b_state  = (float*)(ws + 1048576);       // 33.5 MB
  float* v_buf    = (float*)(ws + 34603008);      // 2 MB
  float* vn_buf   = (float*)(ws + 36700160);      // 256 KB
  float* p_buf    = (float*)(ws + 36962304);      // 256 KB
  float* coef_buf = (float*)(ws + 37224448);      // 2 MB
  float* row_m    = (float*)(ws + 39321600);      // 2 KB
  float* row_inv  = (float*)(ws + 39323648);      // 2 KB
  float* pstat_m  = (float*)(ws + 39325696);      // 512*784*4 = 1.606 MB
  float* pstat_s  = (float*)(ws + 40931328);      // 1.606 MB (end ~42.5 MB)

  // gi_t50 (57.6 MB) overlays [b_state .. pstat] -- all of those are written
  // only AFTER gru completes. gi_click (76.8 MB) + Et (12.8 MB) live in d_out:
  // Et workers (inside gru kernel) write d_out+76.8MB while click blocks read
  // d_out[0..76.8MB) -- disjoint. lg16 (51.25 MB) is written after gru.
  unsigned short* gi_t50   = (unsigned short*)(ws + 1048576);
  unsigned short* gi_click = (unsigned short*)d_out;
  short* Et = (short*)((char*)d_out + 78643200);

  gi_gemm_kernel<<<dim3(700), 512, 0, stream>>>(seq0, seq1, seq2, seq3, item_emb, Wih,
                                                gi_t50, gi_click);
  gru_rec5w_kernel<<<dim3(640), 256, 0, stream>>>(Whh, bih, bhh, gi_t50, gi_click,
                                                  item_emb, Et, e_buf);
  // iter 0: c uniform
  route_kernel<0><<<dim3(128), 256, 0, stream>>>(nullptr, nullptr, e_buf, W, nullptr,
                                                 w_scale, bias_vec, alpha, v_buf, vn_buf);
  logits16s_kernel<<<dim3(782), 512, 0, stream>>>(vn_buf, item_emb, lg16, pstat_m, pstat_s);
  rowstats_p_kernel<<<dim3(512), 256, 0, stream>>>(pstat_m, pstat_s, row_m, row_inv);
  hipMemsetAsync(p_buf, 0, 262144, stream);
  pgemm16_kernel<<<dim3(49, 8), 256, 0, stream>>>(lg16, Et, row_m, row_inv, p_buf);
  coef_kernel<<<dim3(128), 256, 0, stream>>>(p_buf, v_buf, W_coef, coef_buf);
  // iter 1: b1 = delta(coef0); v1
  route_kernel<1><<<dim3(128), 256, 0, stream>>>(nullptr, b_state, e_buf, W, coef_buf,
                                                 w_scale, bias_vec, alpha, v_buf, vn_buf);
  logits16s_kernel<<<dim3(782), 512, 0, stream>>>(vn_buf, item_emb, lg16, pstat_m, pstat_s);
  rowstats_p_kernel<<<dim3(512), 256, 0, stream>>>(pstat_m, pstat_s, row_m, row_inv);
  hipMemsetAsync(p_buf, 0, 262144, stream);
  pgemm16_kernel<<<dim3(49, 8), 256, 0, stream>>>(lg16, Et, row_m, row_inv, p_buf);
  coef_kernel<<<dim3(128), 256, 0, stream>>>(p_buf, v_buf, W_coef, coef_buf);
  // iter 2 (final): b2 = b1 + delta(coef1); v2
  route_kernel<2><<<dim3(128), 256, 0, stream>>>(b_state, nullptr, e_buf, W, coef_buf,
                                                 w_scale, bias_vec, alpha, v_buf, vn_buf);
  logits32_kernel<<<dim3(782), 512, 0, stream>>>(vn_buf, item_emb, out);
}